// Round 3
// baseline (133.490 us; speedup 1.0000x reference)
//
#include <hip/hip_runtime.h>
#include <math.h>

typedef unsigned short u16;
typedef unsigned int   u32;
typedef __attribute__((ext_vector_type(8))) short s8v;   // 8 bf16 (4 VGPRs)
typedef __attribute__((ext_vector_type(4))) float f4v;   // MFMA C/D

#define NHEADS 12
#define SEQ 2048
#define CD 768
#define BB 2
#define QKVD 2304
#define CEXP 0.18033688f      // 0.125 * log2(e)  (scale folded into exp2)
#define DEFER_THR 44.0f       // raw-score units; exp2(44*CEXP) ~ 245, bf16-safe

__device__ inline u16 f2bf(float f) {            // RNE fp32->bf16
    union { float f; unsigned u; } v; v.f = f;
    unsigned r = v.u + 0x7FFFu + ((v.u >> 16) & 1u);
    return (u16)(r >> 16);
}
__device__ inline u32 cvtpk_bf16(float lo, float hi) {  // 2xf32 -> packed 2xbf16
    u32 r;
    asm("v_cvt_pk_bf16_f32 %0, %1, %2" : "=v"(r) : "v"(lo), "v"(hi));
    return r;
}

// async global->LDS, 16B/lane; DST wave-uniform (HW adds lane*16)
#define GLOAD16(SRC, DST) __builtin_amdgcn_global_load_lds(                 \
    (const __attribute__((address_space(1))) void*)(SRC),                   \
    (__attribute__((address_space(3))) void*)(DST), 16, 0, 0)

// XOR swizzle for row-major [R][64] bf16 tiles (128B rows): ushort index
#define SW(r, c) ((((r) << 6) + (c)) ^ (((r) & 7) << 3))

// ---------------------------------------------------------------------------
// fused fp32->bf16 conversion of all three inputs in one launch
// ---------------------------------------------------------------------------
__global__ __launch_bounds__(256)
void cvt3_kernel(const float* __restrict__ a, u16* __restrict__ oa, int na,
                 const float* __restrict__ b, u16* __restrict__ ob, int nb,
                 const float* __restrict__ c, u16* __restrict__ oc) {
    const int i = (blockIdx.x * 256 + threadIdx.x) * 8;
    const float* src; u16* dst;
    if (i < na)           { src = a + i;            dst = oa + i; }
    else if (i < na + nb) { src = b + (i - na);     dst = ob + (i - na); }
    else                  { src = c + (i - na - nb); dst = oc + (i - na - nb); }
    const float4 x = *(const float4*)src;
    const float4 y = *(const float4*)(src + 4);
    s8v o;
    o[0] = (short)f2bf(x.x); o[1] = (short)f2bf(x.y);
    o[2] = (short)f2bf(x.z); o[3] = (short)f2bf(x.w);
    o[4] = (short)f2bf(y.x); o[5] = (short)f2bf(y.y);
    o[6] = (short)f2bf(y.z); o[7] = (short)f2bf(y.w);
    *(s8v*)dst = o;
}

// ---------------------------------------------------------------------------
// C = A @ W^T (+bias). A[M][K], W[N][K] bf16. 128xBN tile, BK=64, 4 waves.
// ---------------------------------------------------------------------------
template<int BN, bool OUT_BF16, bool BIAS>
__global__ __launch_bounds__(256)
void gemm_bf16(const u16* __restrict__ A, const u16* __restrict__ W,
               const float* __restrict__ bias, void* __restrict__ Cout,
               int M, int N, int K) {
    constexpr int NF = BN / 32;        // n-frags per wave
    __shared__ u16 As[8192];           // [128][64] swizzled
    __shared__ u16 Bs[BN * 64];
    const int tid = threadIdx.x;
    const int l  = tid & 63, w = tid >> 6;
    const int wr = w >> 1, wc = w & 1;
    const int lq = l & 15, lg = l >> 4;
    const int rowBase = blockIdx.y << 7, colBase = blockIdx.x * BN;

    f4v acc[4][NF];
    #pragma unroll
    for (int m = 0; m < 4; ++m)
        #pragma unroll
        for (int n = 0; n < NF; ++n)
            #pragma unroll
            for (int r = 0; r < 4; ++r) acc[m][n][r] = 0.f;

    const int chunk = l & 7;
    const int r8    = l >> 3;

    for (int kb = 0; kb < K; kb += 64) {
        __syncthreads();
        #pragma unroll
        for (int j = 0; j < 4; ++j) {
            const int rowA = (w << 5) + (j << 3) + r8;
            const int sc   = (chunk ^ (rowA & 7)) << 3;
            GLOAD16(A + (size_t)(rowBase + rowA) * K + kb + sc,
                    &As[(w << 11) + (j << 9)]);
        }
        #pragma unroll
        for (int j = 0; j < NF; ++j) {
            const int rowB = w * (BN / 4) + (j << 3) + r8;
            const int sc   = (chunk ^ (rowB & 7)) << 3;
            GLOAD16(W + (size_t)(colBase + rowB) * K + kb + sc,
                    &Bs[w * (BN * 16) + (j << 9)]);
        }
        __syncthreads();
        #pragma unroll
        for (int h = 0; h < 2; ++h) {
            const int kc = (h << 5) + (lg << 3);
            s8v af[4], bf[NF];
            #pragma unroll
            for (int m = 0; m < 4; ++m)
                af[m] = *(const s8v*)&As[SW((wr << 6) + (m << 4) + lq, kc)];
            #pragma unroll
            for (int n = 0; n < NF; ++n)
                bf[n] = *(const s8v*)&Bs[SW(wc * (BN / 2) + (n << 4) + lq, kc)];
            #pragma unroll
            for (int m = 0; m < 4; ++m)
                #pragma unroll
                for (int n = 0; n < NF; ++n)
                    acc[m][n] = __builtin_amdgcn_mfma_f32_16x16x32_bf16(
                        af[m], bf[n], acc[m][n], 0, 0, 0);
        }
    }

    #pragma unroll
    for (int m = 0; m < 4; ++m)
        #pragma unroll
        for (int r = 0; r < 4; ++r) {
            const int row = rowBase + (wr << 6) + (m << 4) + (lg << 2) + r;
            #pragma unroll
            for (int n = 0; n < NF; ++n) {
                const int col = colBase + wc * (BN / 2) + (n << 4) + lq;
                float v = acc[m][n][r];
                if (BIAS) v += bias[col];
                if (OUT_BF16) ((u16*)Cout)[(size_t)row * N + col] = f2bf(v);
                else        ((float*)Cout)[(size_t)row * N + col] = v;
            }
        }
}

// ---------------------------------------------------------------------------
// MFMA flash attention with in-block KV-split.
// Block = (b,h, 64 q-rows), 512 thr = 8 waves. Group g = w>>2 handles keys
// [g*1024, g*1024+1024). Partials merged via LDS at the end.
// LDS (u16 idx): K[g] @ g*8192, V[g] @ g*8192+4096, P/Q @ 16384 ([128][64]),
// M/L f32 @ 24576. Group-1 O-spill (f32 [64][64]) aliases group-1 K+V.
// ---------------------------------------------------------------------------
__global__ __launch_bounds__(512, 6)
void attn_mfma(const u16* __restrict__ qkv, u16* __restrict__ outb) {
    __shared__ u16 lds[24832];   // 48.5 KB
    float* Msh  = (float*)(lds + 24576);   // [64]
    float* Lsh  = Msh + 64;                // [64]
    float* Of32 = (float*)(lds + 8192);    // [64][64], aliases group-1 K/V

    const int tid = threadIdx.x;
    const int l = tid & 63, w = tid >> 6;     // w 0..7
    const int g = w >> 2, wl = w & 3;
    const int lq = l & 15, lg = l >> 4;
    const int q0 = blockIdx.x << 6;
    const int bh = blockIdx.y;
    const int b = bh / NHEADS, h = bh % NHEADS;
    const u16* base = qkv + (size_t)b * SEQ * QKVD + h * 192;

    u16* Kl = lds + g * 8192;
    u16* Vl = Kl + 4096;
    u16* PQ = lds + 16384;

    {   // stage Q: 512 threads x 8 u16 covers [64][64]
        const int row = tid >> 3, ch = tid & 7;
        const s8v q = *(const s8v*)(base + (size_t)(q0 + row) * QKVD + (ch << 3));
        *(s8v*)&PQ[SW(row, ch << 3)] = q;
    }
    __syncthreads();
    s8v qf[2];                    // B-frag: col=q (lq of wave's 16), k=d
    #pragma unroll
    for (int h2 = 0; h2 < 2; ++h2)
        qf[h2] = *(const s8v*)&PQ[SW((wl << 4) + lq, (h2 << 5) + (lg << 3))];

    f4v oacc[4];
    #pragma unroll
    for (int db = 0; db < 4; ++db)
        #pragma unroll
        for (int r = 0; r < 4; ++r) oacc[db][r] = 0.f;
    float mrun = -3.0e38f, lrun = 0.f;

    for (int tt = 0; tt < 16; ++tt) {
        const int t = (g << 4) + tt;
        const u16* ksrc = base + (size_t)(t * 64 + l) * QKVD + 64;
        const s8v kr0 = *(const s8v*)(ksrc + (wl << 3));
        const s8v kr1 = *(const s8v*)(ksrc + ((wl + 4) << 3));
        const s8v vr0 = *(const s8v*)(ksrc + 64 + (wl << 3));
        const s8v vr1 = *(const s8v*)(ksrc + 64 + ((wl + 4) << 3));
        __syncthreads();          // prev tile's LDS reads done
        *(s8v*)&Kl[SW(l, (wl << 3))] = kr0;
        *(s8v*)&Kl[SW(l, ((wl + 4) << 3))] = kr1;
        #pragma unroll
        for (int e = 0; e < 8; ++e) {   // V transpose; uniform row/instr -> free
            Vl[SW((wl << 3) + e, l)]       = (u16)vr0[e];
            Vl[SW(((wl + 4) << 3) + e, l)] = (u16)vr1[e];
        }
        __syncthreads();

        // S^T = K Q^T : lane owns q=lq, keys kb*16+lg*4+r (raw scores)
        float p[16];
        #pragma unroll
        for (int kb = 0; kb < 4; ++kb) {
            const s8v k0 = *(const s8v*)&Kl[SW((kb << 4) + lq, (lg << 3))];
            const s8v k1 = *(const s8v*)&Kl[SW((kb << 4) + lq, 32 + (lg << 3))];
            f4v z;
            #pragma unroll
            for (int r = 0; r < 4; ++r) z[r] = 0.f;
            z = __builtin_amdgcn_mfma_f32_16x16x32_bf16(k0, qf[0], z, 0, 0, 0);
            z = __builtin_amdgcn_mfma_f32_16x16x32_bf16(k1, qf[1], z, 0, 0, 0);
            #pragma unroll
            for (int r = 0; r < 4; ++r) p[(kb << 2) + r] = z[r];
        }

        // online softmax, raw units, defer-max
        float mx = p[0];
        #pragma unroll
        for (int i = 1; i < 16; ++i) mx = fmaxf(mx, p[i]);
        mx = fmaxf(mx, __shfl_xor(mx, 16));
        mx = fmaxf(mx, __shfl_xor(mx, 32));
        if (!__all(mx <= mrun + DEFER_THR)) {
            const float mn = fmaxf(mrun, mx);
            const float al = exp2f((mrun - mn) * CEXP);
            mrun = mn;
            float ar[4];
            #pragma unroll
            for (int r = 0; r < 4; ++r) ar[r] = __shfl(al, (lg << 2) + r);
            #pragma unroll
            for (int db = 0; db < 4; ++db)
                #pragma unroll
                for (int r = 0; r < 4; ++r) oacc[db][r] *= ar[r];
            lrun *= al;
        }
        const float mC = -mrun * CEXP;
        float sum = 0.f;
        #pragma unroll
        for (int i = 0; i < 16; ++i) {
            p[i] = exp2f(fmaf(p[i], CEXP, mC));
            sum += p[i];
        }
        sum += __shfl_xor(sum, 16);
        sum += __shfl_xor(sum, 32);
        lrun += sum;

        // P -> bf16 (cvt_pk) -> wave-private LDS rows [w*16, w*16+16)
        #pragma unroll
        for (int kb = 0; kb < 4; ++kb) {
            u32 pw0 = cvtpk_bf16(p[(kb << 2) + 0], p[(kb << 2) + 1]);
            u32 pw1 = cvtpk_bf16(p[(kb << 2) + 2], p[(kb << 2) + 3]);
            u32* dst = (u32*)&PQ[SW((w << 4) + lq, (kb << 4) + (lg << 2))];
            dst[0] = pw0; dst[1] = pw1;
        }
        const s8v pf0 = *(const s8v*)&PQ[SW((w << 4) + lq, (lg << 3))];
        const s8v pf1 = *(const s8v*)&PQ[SW((w << 4) + lq, 32 + (lg << 3))];
        #pragma unroll
        for (int db = 0; db < 4; ++db) {
            const s8v v0 = *(const s8v*)&Vl[SW((db << 4) + lq, (lg << 3))];
            const s8v v1 = *(const s8v*)&Vl[SW((db << 4) + lq, 32 + (lg << 3))];
            oacc[db] = __builtin_amdgcn_mfma_f32_16x16x32_bf16(pf0, v0, oacc[db], 0, 0, 0);
            oacc[db] = __builtin_amdgcn_mfma_f32_16x16x32_bf16(pf1, v1, oacc[db], 0, 0, 0);
        }
    }

    __syncthreads();   // all KV-region reads complete before O-spill aliases it
    if (g == 1) {
        if (lg == 0) { Msh[(wl << 4) + lq] = mrun; Lsh[(wl << 4) + lq] = lrun; }
        #pragma unroll
        for (int db = 0; db < 4; ++db)
            #pragma unroll
            for (int r = 0; r < 4; ++r)
                Of32[(((wl << 4) + (lg << 2) + r) << 6) + (db << 4) + lq] =
                    oacc[db][r];
    }
    __syncthreads();
    if (g == 0) {
        const float m1  = Msh[(wl << 4) + lq];
        const float l1v = Lsh[(wl << 4) + lq];
        const float M   = fmaxf(mrun, m1);
        const float w0  = exp2f((mrun - M) * CEXP);
        const float w1  = exp2f((m1 - M) * CEXP);
        const float inv = 1.f / (lrun * w0 + l1v * w1);
        const float a0 = w0 * inv, a1 = w1 * inv;
        #pragma unroll
        for (int r = 0; r < 4; ++r) {
            const float a0r = __shfl(a0, (lg << 2) + r);
            const float a1r = __shfl(a1, (lg << 2) + r);
            const size_t row = (size_t)b * SEQ + q0 + (wl << 4) + (lg << 2) + r;
            #pragma unroll
            for (int db = 0; db < 4; ++db) {
                const float o1 =
                    Of32[(((wl << 4) + (lg << 2) + r) << 6) + (db << 4) + lq];
                outb[row * CD + h * 64 + (db << 4) + lq] =
                    f2bf(oacc[db][r] * a0r + o1 * a1r);
            }
        }
    }
}

// ---------------------------------------------------------------------------
extern "C" void kernel_launch(void* const* d_in, const int* in_sizes, int n_in,
                              void* d_out, int out_size, void* d_ws, size_t ws_size,
                              hipStream_t stream) {
    const float* x     = (const float*)d_in[0];
    const float* w_qkv = (const float*)d_in[1];
    const float* w_mlp = (const float*)d_in[2];
    const float* b_mlp = (const float*)d_in[3];
    float* out = (float*)d_out;

    const int NX  = BB * SEQ * CD;        // 3,145,728
    const int NWQ = QKVD * CD;            // 1,769,472
    const int NWM = CD * CD;              //   589,824
    const int NQK = BB * SEQ * QKVD;      // 9,437,184

    u16* xb    = (u16*)d_ws;
    u16* wqkvb = xb + NX;
    u16* wmlpb = wqkvb + NWQ;
    u16* qkvb  = wmlpb + NWM;
    u16* attnb = qkvb + NQK;

    cvt3_kernel<<<(NX + NWQ + NWM) / 2048, 256, 0, stream>>>(
        x, xb, NX, w_qkv, wqkvb, NWQ, w_mlp, wmlpb);

    const int M = BB * SEQ;   // 4096
    {   // qkv = x @ w_qkv^T  -> bf16
        dim3 grid(QKVD / 128, M / 128);
        gemm_bf16<128, true, false><<<grid, 256, 0, stream>>>(xb, wqkvb, nullptr,
                                                              qkvb, M, QKVD, CD);
    }
    {   // attention (in-block KV-split, 8 waves)
        dim3 grid(SEQ / 64, BB * NHEADS);
        attn_mfma<<<grid, 512, 0, stream>>>(qkvb, attnb);
    }
    {   // out = attn @ w_mlp^T + b  -> fp32 (128x64 tiles: 384 blocks)
        dim3 grid(CD / 64, M / 128);
        gemm_bf16<64, false, true><<<grid, 256, 0, stream>>>(attnb, wmlpb, b_mlp,
                                                             out, M, CD, CD);
    }
}

// Round 4
// 113.366 us; speedup vs baseline: 1.1775x; 1.1775x over previous
//
#include <hip/hip_runtime.h>
#include <math.h>

typedef unsigned short u16;
typedef unsigned int   u32;
typedef __attribute__((ext_vector_type(8))) short s8v;   // 8 bf16 (4 VGPRs)
typedef __attribute__((ext_vector_type(4))) float f4v;   // MFMA C/D

#define NHEADS 12
#define SEQ 2048
#define CD 768
#define BB 2
#define QKVD 2304
#define CEXP 0.18033688f      // 0.125 * log2(e)  (scale folded into exp2)
#define DEFER_THR 44.0f       // raw-score units; exp2(44*CEXP) ~ 245, bf16-safe

__device__ inline u16 f2bf(float f) {            // RNE fp32->bf16
    union { float f; unsigned u; } v; v.f = f;
    unsigned r = v.u + 0x7FFFu + ((v.u >> 16) & 1u);
    return (u16)(r >> 16);
}
__device__ inline u32 cvtpk_bf16(float lo, float hi) {  // 2xf32 -> packed 2xbf16
    u32 r;
    asm("v_cvt_pk_bf16_f32 %0, %1, %2" : "=v"(r) : "v"(lo), "v"(hi));
    return r;
}

// async global->LDS, 16B/lane; DST wave-uniform (HW adds lane*16)
#define GLOAD16(SRC, DST) __builtin_amdgcn_global_load_lds(                 \
    (const __attribute__((address_space(1))) void*)(SRC),                   \
    (__attribute__((address_space(3))) void*)(DST), 16, 0, 0)

// XOR swizzle for row-major [R][64] bf16 tiles (128B rows): ushort index
#define SW(r, c) ((((r) << 6) + (c)) ^ (((r) & 7) << 3))

// ---------------------------------------------------------------------------
// fused fp32->bf16 conversion of all three inputs in one launch
// ---------------------------------------------------------------------------
__global__ __launch_bounds__(256)
void cvt3_kernel(const float* __restrict__ a, u16* __restrict__ oa, int na,
                 const float* __restrict__ b, u16* __restrict__ ob, int nb,
                 const float* __restrict__ c, u16* __restrict__ oc) {
    const int i = (blockIdx.x * 256 + threadIdx.x) * 8;
    const float* src; u16* dst;
    if (i < na)           { src = a + i;            dst = oa + i; }
    else if (i < na + nb) { src = b + (i - na);     dst = ob + (i - na); }
    else                  { src = c + (i - na - nb); dst = oc + (i - na - nb); }
    const float4 x = *(const float4*)src;
    const float4 y = *(const float4*)(src + 4);
    s8v o;
    o[0] = (short)f2bf(x.x); o[1] = (short)f2bf(x.y);
    o[2] = (short)f2bf(x.z); o[3] = (short)f2bf(x.w);
    o[4] = (short)f2bf(y.x); o[5] = (short)f2bf(y.y);
    o[6] = (short)f2bf(y.z); o[7] = (short)f2bf(y.w);
    *(s8v*)dst = o;
}

// ---------------------------------------------------------------------------
// C = A @ W^T (+bias). A[M][K], W[N][K] bf16. 128xBN tile, BK=64, 4 waves.
// ---------------------------------------------------------------------------
template<int BN, bool OUT_BF16, bool BIAS>
__global__ __launch_bounds__(256)
void gemm_bf16(const u16* __restrict__ A, const u16* __restrict__ W,
               const float* __restrict__ bias, void* __restrict__ Cout,
               int M, int N, int K) {
    constexpr int NF = BN / 32;        // n-frags per wave
    __shared__ u16 As[8192];           // [128][64] swizzled
    __shared__ u16 Bs[BN * 64];
    const int tid = threadIdx.x;
    const int l  = tid & 63, w = tid >> 6;
    const int wr = w >> 1, wc = w & 1;
    const int lq = l & 15, lg = l >> 4;
    const int rowBase = blockIdx.y << 7, colBase = blockIdx.x * BN;

    f4v acc[4][NF];
    #pragma unroll
    for (int m = 0; m < 4; ++m)
        #pragma unroll
        for (int n = 0; n < NF; ++n)
            #pragma unroll
            for (int r = 0; r < 4; ++r) acc[m][n][r] = 0.f;

    const int chunk = l & 7;
    const int r8    = l >> 3;

    for (int kb = 0; kb < K; kb += 64) {
        __syncthreads();
        #pragma unroll
        for (int j = 0; j < 4; ++j) {
            const int rowA = (w << 5) + (j << 3) + r8;
            const int sc   = (chunk ^ (rowA & 7)) << 3;
            GLOAD16(A + (size_t)(rowBase + rowA) * K + kb + sc,
                    &As[(w << 11) + (j << 9)]);
        }
        #pragma unroll
        for (int j = 0; j < NF; ++j) {
            const int rowB = w * (BN / 4) + (j << 3) + r8;
            const int sc   = (chunk ^ (rowB & 7)) << 3;
            GLOAD16(W + (size_t)(colBase + rowB) * K + kb + sc,
                    &Bs[w * (BN * 16) + (j << 9)]);
        }
        __syncthreads();
        #pragma unroll
        for (int h = 0; h < 2; ++h) {
            const int kc = (h << 5) + (lg << 3);
            s8v af[4], bf[NF];
            #pragma unroll
            for (int m = 0; m < 4; ++m)
                af[m] = *(const s8v*)&As[SW((wr << 6) + (m << 4) + lq, kc)];
            #pragma unroll
            for (int n = 0; n < NF; ++n)
                bf[n] = *(const s8v*)&Bs[SW(wc * (BN / 2) + (n << 4) + lq, kc)];
            #pragma unroll
            for (int m = 0; m < 4; ++m)
                #pragma unroll
                for (int n = 0; n < NF; ++n)
                    acc[m][n] = __builtin_amdgcn_mfma_f32_16x16x32_bf16(
                        af[m], bf[n], acc[m][n], 0, 0, 0);
        }
    }

    #pragma unroll
    for (int m = 0; m < 4; ++m)
        #pragma unroll
        for (int r = 0; r < 4; ++r) {
            const int row = rowBase + (wr << 6) + (m << 4) + (lg << 2) + r;
            #pragma unroll
            for (int n = 0; n < NF; ++n) {
                const int col = colBase + wc * (BN / 2) + (n << 4) + lq;
                float v = acc[m][n][r];
                if (BIAS) v += bias[col];
                if (OUT_BF16) ((u16*)Cout)[(size_t)row * N + col] = f2bf(v);
                else        ((float*)Cout)[(size_t)row * N + col] = v;
            }
        }
}

// ---------------------------------------------------------------------------
// MFMA flash attention. Block = (b,h, 64 q-rows), 4 waves x 16 q-rows.
// Swapped QK^T: lane owns q = l&15, 16 keys. Softmax denominator computed by
// MFMA (ones-column in Vt rows 64..79). Defer-max with local-only check:
// steady-state tiles have zero cross-lane ops. P bounced via QP LDS.
// LDS: K 8KB + Vt 10KB ([80][64], rows 64..79 const) + QP 8KB = 26KB.
// ---------------------------------------------------------------------------
__global__ __launch_bounds__(256)
void attn_mfma(const u16* __restrict__ qkv, u16* __restrict__ outb) {
    __shared__ u16 Klds[4096];   // [key][d] swz
    __shared__ u16 Vt[5120];     // [d'][key] swz; d'=64 ones, 65..79 zero
    __shared__ u16 QP[4096];     // [qrow][d] swz; later P [qrow][key]
    const int tid = threadIdx.x;
    const int l = tid & 63, w = tid >> 6;
    const int lq = l & 15, lg = l >> 4;
    const int q0 = blockIdx.x << 6;
    const int bh = blockIdx.y;
    const int b = bh / NHEADS, h = bh % NHEADS;
    const u16* base = qkv + (size_t)b * SEQ * QKVD + h * 192;

    {   // init constant rows 64..79 of Vt (row 64 = 1.0, rest 0); once
        const int r = 64 + (tid >> 4);
        const int c = (tid & 15) << 2;
        const u16 v = (r == 64) ? (u16)0x3F80 : (u16)0;
        u16* dst = &Vt[SW(r, c)];
        dst[0] = v; dst[1] = v; dst[2] = v; dst[3] = v;
    }
    {   // stage Q: thread covers qrow=l, chunks {w, w+4}
        const u16* qsrc = base + (size_t)(q0 + l) * QKVD;
        const s8v q1 = *(const s8v*)(qsrc + (w << 3));
        const s8v q2 = *(const s8v*)(qsrc + ((w + 4) << 3));
        *(s8v*)&QP[SW(l, (w << 3))] = q1;
        *(s8v*)&QP[SW(l, ((w + 4) << 3))] = q2;
    }
    __syncthreads();
    s8v qf[2];                    // B-frag: col=q (lq), k=d
    #pragma unroll
    for (int h2 = 0; h2 < 2; ++h2)
        qf[h2] = *(const s8v*)&QP[SW((w << 4) + lq, (h2 << 5) + (lg << 3))];

    f4v oacc[4], osum;
    #pragma unroll
    for (int db = 0; db < 4; ++db)
        #pragma unroll
        for (int r = 0; r < 4; ++r) oacc[db][r] = 0.f;
    #pragma unroll
    for (int r = 0; r < 4; ++r) osum[r] = 0.f;
    float mrun = -3.0e38f;

    for (int t = 0; t < 32; ++t) {
        // K/V tile global loads into regs (issued before barrier: overlap)
        const u16* ksrc = base + (size_t)(t * 64 + l) * QKVD + 64;
        const s8v kr0 = *(const s8v*)(ksrc + (w << 3));
        const s8v kr1 = *(const s8v*)(ksrc + ((w + 4) << 3));
        const s8v vr0 = *(const s8v*)(ksrc + 64 + (w << 3));
        const s8v vr1 = *(const s8v*)(ksrc + 64 + ((w + 4) << 3));
        __syncthreads();          // prev tile's LDS reads done
        *(s8v*)&Klds[SW(l, (w << 3))] = kr0;
        *(s8v*)&Klds[SW(l, ((w + 4) << 3))] = kr1;
        #pragma unroll
        for (int e = 0; e < 8; ++e) {   // V transpose (rows 0..63 only)
            Vt[SW((w << 3) + e, l)]       = (u16)vr0[e];
            Vt[SW(((w + 4) << 3) + e, l)] = (u16)vr1[e];
        }
        __syncthreads();

        // S^T = K Q^T : lane owns q=lq, keys kb*16+lg*4+r (raw scores)
        float p[16];
        __builtin_amdgcn_s_setprio(1);
        #pragma unroll
        for (int kb = 0; kb < 4; ++kb) {
            const s8v k0 = *(const s8v*)&Klds[SW((kb << 4) + lq, (lg << 3))];
            const s8v k1 = *(const s8v*)&Klds[SW((kb << 4) + lq, 32 + (lg << 3))];
            f4v z;
            #pragma unroll
            for (int r = 0; r < 4; ++r) z[r] = 0.f;
            z = __builtin_amdgcn_mfma_f32_16x16x32_bf16(k0, qf[0], z, 0, 0, 0);
            z = __builtin_amdgcn_mfma_f32_16x16x32_bf16(k1, qf[1], z, 0, 0, 0);
            #pragma unroll
            for (int r = 0; r < 4; ++r) p[(kb << 2) + r] = z[r];
        }
        __builtin_amdgcn_s_setprio(0);

        // defer-max: local check only (ballot covers cross-lane)
        float mx = p[0];
        #pragma unroll
        for (int i = 1; i < 16; ++i) mx = fmaxf(mx, p[i]);
        if (!__all(mx <= mrun + DEFER_THR)) {
            mx = fmaxf(mx, __shfl_xor(mx, 16));
            mx = fmaxf(mx, __shfl_xor(mx, 32));
            const float mn = fmaxf(mrun, mx);
            const float al = exp2f((mrun - mn) * CEXP);
            mrun = mn;
            float ar[4];
            #pragma unroll
            for (int r = 0; r < 4; ++r) ar[r] = __shfl(al, (lg << 2) + r);
            #pragma unroll
            for (int db = 0; db < 4; ++db)
                #pragma unroll
                for (int r = 0; r < 4; ++r) oacc[db][r] *= ar[r];
            #pragma unroll
            for (int r = 0; r < 4; ++r) osum[r] *= ar[r];
        }
        const float mC = -mrun * CEXP;
        #pragma unroll
        for (int i = 0; i < 16; ++i) p[i] = exp2f(fmaf(p[i], CEXP, mC));

        // P -> bf16 (cvt_pk) -> wave-private LDS rows [w*16, w*16+16)
        #pragma unroll
        for (int kb = 0; kb < 4; ++kb) {
            u32 pw0 = cvtpk_bf16(p[(kb << 2) + 0], p[(kb << 2) + 1]);
            u32 pw1 = cvtpk_bf16(p[(kb << 2) + 2], p[(kb << 2) + 3]);
            u32* dst = (u32*)&QP[SW((w << 4) + lq, (kb << 4) + (lg << 2))];
            dst[0] = pw0; dst[1] = pw1;
        }
        const s8v pf0 = *(const s8v*)&QP[SW((w << 4) + lq, (lg << 3))];
        const s8v pf1 = *(const s8v*)&QP[SW((w << 4) + lq, 32 + (lg << 3))];
        // PV (+ denominator via ones-column, db=4)
        __builtin_amdgcn_s_setprio(1);
        #pragma unroll
        for (int db = 0; db < 5; ++db) {
            const s8v v0 = *(const s8v*)&Vt[SW((db << 4) + lq, (lg << 3))];
            const s8v v1 = *(const s8v*)&Vt[SW((db << 4) + lq, 32 + (lg << 3))];
            f4v acc = (db == 4) ? osum : oacc[db];
            acc = __builtin_amdgcn_mfma_f32_16x16x32_bf16(pf0, v0, acc, 0, 0, 0);
            acc = __builtin_amdgcn_mfma_f32_16x16x32_bf16(pf1, v1, acc, 0, 0, 0);
            if (db == 4) osum = acc; else oacc[db] = acc;
        }
        __builtin_amdgcn_s_setprio(0);
    }

    // epilogue: O[q'][d], q' = lg*4+r, d = db*16+lq; denom in lanes lq==0
    #pragma unroll
    for (int r = 0; r < 4; ++r) {
        const float li = __shfl(osum[r], l & 48);   // lane (lg,0) holds row sum
        const float inv = 1.f / li;
        const size_t row = (size_t)b * SEQ + q0 + (w << 4) + (lg << 2) + r;
        #pragma unroll
        for (int db = 0; db < 4; ++db)
            outb[row * CD + h * 64 + (db << 4) + lq] = f2bf(oacc[db][r] * inv);
    }
}

// ---------------------------------------------------------------------------
extern "C" void kernel_launch(void* const* d_in, const int* in_sizes, int n_in,
                              void* d_out, int out_size, void* d_ws, size_t ws_size,
                              hipStream_t stream) {
    const float* x     = (const float*)d_in[0];
    const float* w_qkv = (const float*)d_in[1];
    const float* w_mlp = (const float*)d_in[2];
    const float* b_mlp = (const float*)d_in[3];
    float* out = (float*)d_out;

    const int NX  = BB * SEQ * CD;        // 3,145,728
    const int NWQ = QKVD * CD;            // 1,769,472
    const int NWM = CD * CD;              //   589,824
    const int NQK = BB * SEQ * QKVD;      // 9,437,184

    u16* xb    = (u16*)d_ws;
    u16* wqkvb = xb + NX;
    u16* wmlpb = wqkvb + NWQ;
    u16* qkvb  = wmlpb + NWM;
    u16* attnb = qkvb + NQK;

    cvt3_kernel<<<(NX + NWQ + NWM) / 2048, 256, 0, stream>>>(
        x, xb, NX, w_qkv, wqkvb, NWQ, w_mlp, wmlpb);

    const int M = BB * SEQ;   // 4096
    {   // qkv = x @ w_qkv^T  -> bf16
        dim3 grid(QKVD / 128, M / 128);
        gemm_bf16<128, true, false><<<grid, 256, 0, stream>>>(xb, wqkvb, nullptr,
                                                              qkvb, M, QKVD, CD);
    }
    {   // attention
        dim3 grid(SEQ / 64, BB * NHEADS);
        attn_mfma<<<grid, 256, 0, stream>>>(qkvb, attnb);
    }
    {   // out = attn @ w_mlp^T + b  -> fp32 (128x64 tiles: 384 blocks)
        dim3 grid(CD / 64, M / 128);
        gemm_bf16<64, false, true><<<grid, 256, 0, stream>>>(attnb, wmlpb, b_mlp,
                                                             out, M, CD, CD);
    }
}

// Round 5
// 111.984 us; speedup vs baseline: 1.1920x; 1.0123x over previous
//
#include <hip/hip_runtime.h>
#include <math.h>

typedef unsigned short u16;
typedef unsigned int   u32;
typedef __attribute__((ext_vector_type(8))) short s8v;   // 8 bf16 (4 VGPRs)
typedef __attribute__((ext_vector_type(4))) float f4v;   // MFMA C/D

#define NHEADS 12
#define SEQ 2048
#define CD 768
#define BB 2
#define QKVD 2304
#define CEXP 0.18033688f      // 0.125 * log2(e)  (scale folded into exp2)
#define DEFER_THR 44.0f       // raw-score units; exp2(44*CEXP) ~ 245, bf16-safe

__device__ inline u16 f2bf(float f) {            // RNE fp32->bf16
    union { float f; unsigned u; } v; v.f = f;
    unsigned r = v.u + 0x7FFFu + ((v.u >> 16) & 1u);
    return (u16)(r >> 16);
}
__device__ inline u32 cvtpk_bf16(float lo, float hi) {  // 2xf32 -> packed 2xbf16
    u32 r;
    asm("v_cvt_pk_bf16_f32 %0, %1, %2" : "=v"(r) : "v"(lo), "v"(hi));
    return r;
}

// async global->LDS, 16B/lane; DST wave-uniform (HW adds lane*16)
#define GLOAD16(SRC, DST) __builtin_amdgcn_global_load_lds(                 \
    (const __attribute__((address_space(1))) void*)(SRC),                   \
    (__attribute__((address_space(3))) void*)(DST), 16, 0, 0)

// XOR swizzle for row-major [R][64] bf16 tiles (128B rows): ushort index
#define SW(r, c) ((((r) << 6) + (c)) ^ (((r) & 7) << 3))

// ---------------------------------------------------------------------------
// fused fp32->bf16 conversion of all three inputs in one launch
// ---------------------------------------------------------------------------
__global__ __launch_bounds__(256)
void cvt3_kernel(const float* __restrict__ a, u16* __restrict__ oa, int na,
                 const float* __restrict__ b, u16* __restrict__ ob, int nb,
                 const float* __restrict__ c, u16* __restrict__ oc) {
    const int i = (blockIdx.x * 256 + threadIdx.x) * 8;
    const float* src; u16* dst;
    if (i < na)           { src = a + i;            dst = oa + i; }
    else if (i < na + nb) { src = b + (i - na);     dst = ob + (i - na); }
    else                  { src = c + (i - na - nb); dst = oc + (i - na - nb); }
    const float4 x = *(const float4*)src;
    const float4 y = *(const float4*)(src + 4);
    s8v o;
    o[0] = (short)f2bf(x.x); o[1] = (short)f2bf(x.y);
    o[2] = (short)f2bf(x.z); o[3] = (short)f2bf(x.w);
    o[4] = (short)f2bf(y.x); o[5] = (short)f2bf(y.y);
    o[6] = (short)f2bf(y.z); o[7] = (short)f2bf(y.w);
    *(s8v*)dst = o;
}

// ---------------------------------------------------------------------------
// C = A @ W^T (+bias). A[M][K], W[N][K] bf16. 128xBN tile, BK=64, 4 waves.
// ---------------------------------------------------------------------------
template<int BN, bool OUT_BF16, bool BIAS>
__global__ __launch_bounds__(256)
void gemm_bf16(const u16* __restrict__ A, const u16* __restrict__ W,
               const float* __restrict__ bias, void* __restrict__ Cout,
               int M, int N, int K) {
    constexpr int NF = BN / 32;        // n-frags per wave
    __shared__ u16 As[8192];           // [128][64] swizzled
    __shared__ u16 Bs[BN * 64];
    const int tid = threadIdx.x;
    const int l  = tid & 63, w = tid >> 6;
    const int wr = w >> 1, wc = w & 1;
    const int lq = l & 15, lg = l >> 4;
    const int rowBase = blockIdx.y << 7, colBase = blockIdx.x * BN;

    f4v acc[4][NF];
    #pragma unroll
    for (int m = 0; m < 4; ++m)
        #pragma unroll
        for (int n = 0; n < NF; ++n)
            #pragma unroll
            for (int r = 0; r < 4; ++r) acc[m][n][r] = 0.f;

    const int chunk = l & 7;
    const int r8    = l >> 3;

    for (int kb = 0; kb < K; kb += 64) {
        __syncthreads();
        #pragma unroll
        for (int j = 0; j < 4; ++j) {
            const int rowA = (w << 5) + (j << 3) + r8;
            const int sc   = (chunk ^ (rowA & 7)) << 3;
            GLOAD16(A + (size_t)(rowBase + rowA) * K + kb + sc,
                    &As[(w << 11) + (j << 9)]);
        }
        #pragma unroll
        for (int j = 0; j < NF; ++j) {
            const int rowB = w * (BN / 4) + (j << 3) + r8;
            const int sc   = (chunk ^ (rowB & 7)) << 3;
            GLOAD16(W + (size_t)(colBase + rowB) * K + kb + sc,
                    &Bs[w * (BN * 16) + (j << 9)]);
        }
        __syncthreads();
        #pragma unroll
        for (int h = 0; h < 2; ++h) {
            const int kc = (h << 5) + (lg << 3);
            s8v af[4], bf[NF];
            #pragma unroll
            for (int m = 0; m < 4; ++m)
                af[m] = *(const s8v*)&As[SW((wr << 6) + (m << 4) + lq, kc)];
            #pragma unroll
            for (int n = 0; n < NF; ++n)
                bf[n] = *(const s8v*)&Bs[SW(wc * (BN / 2) + (n << 4) + lq, kc)];
            #pragma unroll
            for (int m = 0; m < 4; ++m)
                #pragma unroll
                for (int n = 0; n < NF; ++n)
                    acc[m][n] = __builtin_amdgcn_mfma_f32_16x16x32_bf16(
                        af[m], bf[n], acc[m][n], 0, 0, 0);
        }
    }

    #pragma unroll
    for (int m = 0; m < 4; ++m)
        #pragma unroll
        for (int r = 0; r < 4; ++r) {
            const int row = rowBase + (wr << 6) + (m << 4) + (lg << 2) + r;
            #pragma unroll
            for (int n = 0; n < NF; ++n) {
                const int col = colBase + wc * (BN / 2) + (n << 4) + lq;
                float v = acc[m][n][r];
                if (BIAS) v += bias[col];
                if (OUT_BF16) ((u16*)Cout)[(size_t)row * N + col] = f2bf(v);
                else        ((float*)Cout)[(size_t)row * N + col] = v;
            }
        }
}

// ---------------------------------------------------------------------------
// MFMA flash attention. Block = (b,h, 64 q-rows), 4 waves x 16 q-rows.
// Swapped QK^T: lane owns q = l&15, 16 keys. Softmax denominator via MFMA
// ones-column (Vt rows 64..79). Defer-max with local-only check.
// T14 async-STAGE: tile t+1's K/V global loads issued at loop top (full-iter
// latency cover); double-buffered K/V LDS -> ONE barrier per tile.
// LDS: K 2x8KB + Vt 2x10KB + QP 8KB = 44KB -> 3 blocks/CU (grid-capped).
// ---------------------------------------------------------------------------
__global__ __launch_bounds__(256)
void attn_mfma(const u16* __restrict__ qkv, u16* __restrict__ outb) {
    __shared__ u16 Klds[8192];    // 2 x [64][64] swz
    __shared__ u16 Vt[10240];     // 2 x [80][64] swz; rows 64..79 const
    __shared__ u16 QP[4096];      // Q staging, then P bounce
    const int tid = threadIdx.x;
    const int l = tid & 63, w = tid >> 6;
    const int lq = l & 15, lg = l >> 4;
    const int q0 = blockIdx.x << 6;
    const int bh = blockIdx.y;
    const int b = bh / NHEADS, h = bh % NHEADS;
    const u16* base = qkv + (size_t)b * SEQ * QKVD + h * 192;

    {   // init constant rows 64..79 of both Vt buffers (row 64 = 1.0, rest 0)
        const int r = 64 + (tid >> 4);
        const int c = (tid & 15) << 2;
        const u16 v = (r == 64) ? (u16)0x3F80 : (u16)0;
        #pragma unroll
        for (int pb = 0; pb < 2; ++pb) {
            u16* dst = &Vt[pb * 5120 + SW(r, c)];
            dst[0] = v; dst[1] = v; dst[2] = v; dst[3] = v;
        }
    }
    {   // stage Q: thread covers qrow=l, chunks {w, w+4}
        const u16* qsrc = base + (size_t)(q0 + l) * QKVD;
        const s8v q1 = *(const s8v*)(qsrc + (w << 3));
        const s8v q2 = *(const s8v*)(qsrc + ((w + 4) << 3));
        *(s8v*)&QP[SW(l, (w << 3))] = q1;
        *(s8v*)&QP[SW(l, ((w + 4) << 3))] = q2;
    }

    // prologue: prefetch tile 0 into regs
    s8v ck0, ck1, cv0, cv1;
    {
        const u16* ksrc = base + (size_t)l * QKVD + 64;
        ck0 = *(const s8v*)(ksrc + (w << 3));
        ck1 = *(const s8v*)(ksrc + ((w + 4) << 3));
        cv0 = *(const s8v*)(ksrc + 64 + (w << 3));
        cv1 = *(const s8v*)(ksrc + 64 + ((w + 4) << 3));
    }

    __syncthreads();
    s8v qf[2];                    // B-frag: col=q (lq), k=d
    #pragma unroll
    for (int h2 = 0; h2 < 2; ++h2)
        qf[h2] = *(const s8v*)&QP[SW((w << 4) + lq, (h2 << 5) + (lg << 3))];

    f4v oacc[4], osum;
    #pragma unroll
    for (int db = 0; db < 4; ++db)
        #pragma unroll
        for (int r = 0; r < 4; ++r) oacc[db][r] = 0.f;
    #pragma unroll
    for (int r = 0; r < 4; ++r) osum[r] = 0.f;
    float mrun = -3.0e38f;

    for (int t = 0; t < 32; ++t) {
        u16* Kc = Klds + ((t & 1) << 12);
        u16* Vc = Vt + (t & 1) * 5120;

        // prefetch tile t+1 (consumed next iteration -> full-iter cover)
        s8v nk0, nk1, nv0, nv1;
        if (t < 31) {
            const u16* ksrc = base + (size_t)((t + 1) * 64 + l) * QKVD + 64;
            nk0 = *(const s8v*)(ksrc + (w << 3));
            nk1 = *(const s8v*)(ksrc + ((w + 4) << 3));
            nv0 = *(const s8v*)(ksrc + 64 + (w << 3));
            nv1 = *(const s8v*)(ksrc + 64 + ((w + 4) << 3));
        }

        // write tile t into buffer (t&1); other waves still read buffer (t^1)
        *(s8v*)&Kc[SW(l, (w << 3))] = ck0;
        *(s8v*)&Kc[SW(l, ((w + 4) << 3))] = ck1;
        #pragma unroll
        for (int e = 0; e < 8; ++e) {   // V transpose; uniform row/instr
            Vc[SW((w << 3) + e, l)]       = (u16)cv0[e];
            Vc[SW(((w + 4) << 3) + e, l)] = (u16)cv1[e];
        }
        __syncthreads();          // single barrier per tile

        // S^T = K Q^T : lane owns q=lq, keys kb*16+lg*4+r (raw scores)
        float p[16];
        __builtin_amdgcn_s_setprio(1);
        #pragma unroll
        for (int kb = 0; kb < 4; ++kb) {
            const s8v k0 = *(const s8v*)&Kc[SW((kb << 4) + lq, (lg << 3))];
            const s8v k1 = *(const s8v*)&Kc[SW((kb << 4) + lq, 32 + (lg << 3))];
            f4v z;
            #pragma unroll
            for (int r = 0; r < 4; ++r) z[r] = 0.f;
            z = __builtin_amdgcn_mfma_f32_16x16x32_bf16(k0, qf[0], z, 0, 0, 0);
            z = __builtin_amdgcn_mfma_f32_16x16x32_bf16(k1, qf[1], z, 0, 0, 0);
            #pragma unroll
            for (int r = 0; r < 4; ++r) p[(kb << 2) + r] = z[r];
        }
        __builtin_amdgcn_s_setprio(0);

        // defer-max: local check only (ballot covers cross-lane)
        float mx = p[0];
        #pragma unroll
        for (int i = 1; i < 16; ++i) mx = fmaxf(mx, p[i]);
        if (!__all(mx <= mrun + DEFER_THR)) {
            mx = fmaxf(mx, __shfl_xor(mx, 16));
            mx = fmaxf(mx, __shfl_xor(mx, 32));
            const float mn = fmaxf(mrun, mx);
            const float al = exp2f((mrun - mn) * CEXP);
            mrun = mn;
            float ar[4];
            #pragma unroll
            for (int r = 0; r < 4; ++r) ar[r] = __shfl(al, (lg << 2) + r);
            #pragma unroll
            for (int db = 0; db < 4; ++db)
                #pragma unroll
                for (int r = 0; r < 4; ++r) oacc[db][r] *= ar[r];
            #pragma unroll
            for (int r = 0; r < 4; ++r) osum[r] *= ar[r];
        }
        const float mC = -mrun * CEXP;
        #pragma unroll
        for (int i = 0; i < 16; ++i) p[i] = exp2f(fmaf(p[i], CEXP, mC));

        // P -> bf16 (cvt_pk) -> wave-private LDS rows [w*16, w*16+16)
        #pragma unroll
        for (int kb = 0; kb < 4; ++kb) {
            u32 pw0 = cvtpk_bf16(p[(kb << 2) + 0], p[(kb << 2) + 1]);
            u32 pw1 = cvtpk_bf16(p[(kb << 2) + 2], p[(kb << 2) + 3]);
            u32* dst = (u32*)&QP[SW((w << 4) + lq, (kb << 4) + (lg << 2))];
            dst[0] = pw0; dst[1] = pw1;
        }
        const s8v pf0 = *(const s8v*)&QP[SW((w << 4) + lq, (lg << 3))];
        const s8v pf1 = *(const s8v*)&QP[SW((w << 4) + lq, 32 + (lg << 3))];
        // PV (+ denominator via ones-column, db=4)
        __builtin_amdgcn_s_setprio(1);
        #pragma unroll
        for (int db = 0; db < 5; ++db) {
            const s8v v0 = *(const s8v*)&Vc[SW((db << 4) + lq, (lg << 3))];
            const s8v v1 = *(const s8v*)&Vc[SW((db << 4) + lq, 32 + (lg << 3))];
            f4v acc = (db == 4) ? osum : oacc[db];
            acc = __builtin_amdgcn_mfma_f32_16x16x32_bf16(pf0, v0, acc, 0, 0, 0);
            acc = __builtin_amdgcn_mfma_f32_16x16x32_bf16(pf1, v1, acc, 0, 0, 0);
            if (db == 4) osum = acc; else oacc[db] = acc;
        }
        __builtin_amdgcn_s_setprio(0);

        ck0 = nk0; ck1 = nk1; cv0 = nv0; cv1 = nv1;
    }

    // epilogue: O[q'][d], q' = lg*4+r, d = db*16+lq; denom held by lanes lq==0
    #pragma unroll
    for (int r = 0; r < 4; ++r) {
        const float li = __shfl(osum[r], l & 48);   // lane (lg,0) holds row sum
        const float inv = 1.f / li;
        const size_t row = (size_t)b * SEQ + q0 + (w << 4) + (lg << 2) + r;
        #pragma unroll
        for (int db = 0; db < 4; ++db)
            outb[row * CD + h * 64 + (db << 4) + lq] = f2bf(oacc[db][r] * inv);
    }
}

// ---------------------------------------------------------------------------
extern "C" void kernel_launch(void* const* d_in, const int* in_sizes, int n_in,
                              void* d_out, int out_size, void* d_ws, size_t ws_size,
                              hipStream_t stream) {
    const float* x     = (const float*)d_in[0];
    const float* w_qkv = (const float*)d_in[1];
    const float* w_mlp = (const float*)d_in[2];
    const float* b_mlp = (const float*)d_in[3];
    float* out = (float*)d_out;

    const int NX  = BB * SEQ * CD;        // 3,145,728
    const int NWQ = QKVD * CD;            // 1,769,472
    const int NWM = CD * CD;              //   589,824
    const int NQK = BB * SEQ * QKVD;      // 9,437,184

    u16* xb    = (u16*)d_ws;
    u16* wqkvb = xb + NX;
    u16* wmlpb = wqkvb + NWQ;
    u16* qkvb  = wmlpb + NWM;
    u16* attnb = qkvb + NQK;

    cvt3_kernel<<<(NX + NWQ + NWM) / 2048, 256, 0, stream>>>(
        x, xb, NX, w_qkv, wqkvb, NWQ, w_mlp, wmlpb);

    const int M = BB * SEQ;   // 4096
    {   // qkv = x @ w_qkv^T  -> bf16
        dim3 grid(QKVD / 128, M / 128);
        gemm_bf16<128, true, false><<<grid, 256, 0, stream>>>(xb, wqkvb, nullptr,
                                                              qkvb, M, QKVD, CD);
    }
    {   // attention
        dim3 grid(SEQ / 64, BB * NHEADS);
        attn_mfma<<<grid, 256, 0, stream>>>(qkvb, attnb);
    }
    {   // out = attn @ w_mlp^T + b  -> fp32 (128x64 tiles: 384 blocks)
        dim3 grid(CD / 64, M / 128);
        gemm_bf16<64, false, true><<<grid, 256, 0, stream>>>(attnb, wmlpb, b_mlp,
                                                             out, M, CD, CD);
    }
}

// Round 6
// 108.169 us; speedup vs baseline: 1.2341x; 1.0353x over previous
//
#include <hip/hip_runtime.h>
#include <math.h>

typedef unsigned short u16;
typedef unsigned int   u32;
typedef __attribute__((ext_vector_type(8))) short s8v;   // 8 bf16 (4 VGPRs)
typedef __attribute__((ext_vector_type(2))) unsigned int u32x2;
typedef __attribute__((ext_vector_type(4))) float f4v;   // MFMA C/D

#define NHEADS 12
#define SEQ 2048
#define CD 768
#define BB 2
#define QKVD 2304
#define CEXP 0.18033688f      // 0.125 * log2(e)
#define DEFER_THR 44.0f       // exp2(44*CEXP) ~ 245, bf16-safe

__device__ inline u16 f2bf(float f) {            // RNE fp32->bf16
    union { float f; unsigned u; } v; v.f = f;
    unsigned r = v.u + 0x7FFFu + ((v.u >> 16) & 1u);
    return (u16)(r >> 16);
}
__device__ inline u32 cvtpk_bf16(float lo, float hi) {
    u32 r;
    asm("v_cvt_pk_bf16_f32 %0, %1, %2" : "=v"(r) : "v"(lo), "v"(hi));
    return r;
}

#define GLOAD16(SRC, DST) __builtin_amdgcn_global_load_lds(                 \
    (const __attribute__((address_space(1))) void*)(SRC),                   \
    (__attribute__((address_space(3))) void*)(DST), 16, 0, 0)

// XOR swizzle for row-major [R][64] bf16 tiles (128B rows): u16 index
#define SW(r, c) ((((r) << 6) + (c)) ^ (((r) & 7) << 3))

// ---------------------------------------------------------------------------
__global__ __launch_bounds__(256)
void cvt3_kernel(const float* __restrict__ a, u16* __restrict__ oa, int na,
                 const float* __restrict__ b, u16* __restrict__ ob, int nb,
                 const float* __restrict__ c, u16* __restrict__ oc) {
    const int i = (blockIdx.x * 256 + threadIdx.x) * 8;
    const float* src; u16* dst;
    if (i < na)           { src = a + i;            dst = oa + i; }
    else if (i < na + nb) { src = b + (i - na);     dst = ob + (i - na); }
    else                  { src = c + (i - na - nb); dst = oc + (i - na - nb); }
    const float4 x = *(const float4*)src;
    const float4 y = *(const float4*)(src + 4);
    s8v o;
    o[0] = (short)f2bf(x.x); o[1] = (short)f2bf(x.y);
    o[2] = (short)f2bf(x.z); o[3] = (short)f2bf(x.w);
    o[4] = (short)f2bf(y.x); o[5] = (short)f2bf(y.y);
    o[6] = (short)f2bf(y.z); o[7] = (short)f2bf(y.w);
    *(s8v*)dst = o;
}

// ---------------------------------------------------------------------------
// C = A @ W^T (+bias). 128xBN tile, BK=64, 4 waves (unchanged from r5).
// ---------------------------------------------------------------------------
template<int BN, bool OUT_BF16, bool BIAS>
__global__ __launch_bounds__(256)
void gemm_bf16(const u16* __restrict__ A, const u16* __restrict__ W,
               const float* __restrict__ bias, void* __restrict__ Cout,
               int M, int N, int K) {
    constexpr int NF = BN / 32;
    __shared__ u16 As[8192];
    __shared__ u16 Bs[BN * 64];
    const int tid = threadIdx.x;
    const int l  = tid & 63, w = tid >> 6;
    const int wr = w >> 1, wc = w & 1;
    const int lq = l & 15, lg = l >> 4;
    const int rowBase = blockIdx.y << 7, colBase = blockIdx.x * BN;

    f4v acc[4][NF];
    #pragma unroll
    for (int m = 0; m < 4; ++m)
        #pragma unroll
        for (int n = 0; n < NF; ++n)
            #pragma unroll
            for (int r = 0; r < 4; ++r) acc[m][n][r] = 0.f;

    const int chunk = l & 7;
    const int r8    = l >> 3;

    for (int kb = 0; kb < K; kb += 64) {
        __syncthreads();
        #pragma unroll
        for (int j = 0; j < 4; ++j) {
            const int rowA = (w << 5) + (j << 3) + r8;
            const int sc   = (chunk ^ (rowA & 7)) << 3;
            GLOAD16(A + (size_t)(rowBase + rowA) * K + kb + sc,
                    &As[(w << 11) + (j << 9)]);
        }
        #pragma unroll
        for (int j = 0; j < NF; ++j) {
            const int rowB = w * (BN / 4) + (j << 3) + r8;
            const int sc   = (chunk ^ (rowB & 7)) << 3;
            GLOAD16(W + (size_t)(colBase + rowB) * K + kb + sc,
                    &Bs[w * (BN * 16) + (j << 9)]);
        }
        __syncthreads();
        #pragma unroll
        for (int h = 0; h < 2; ++h) {
            const int kc = (h << 5) + (lg << 3);
            s8v af[4], bf[NF];
            #pragma unroll
            for (int m = 0; m < 4; ++m)
                af[m] = *(const s8v*)&As[SW((wr << 6) + (m << 4) + lq, kc)];
            #pragma unroll
            for (int n = 0; n < NF; ++n)
                bf[n] = *(const s8v*)&Bs[SW(wc * (BN / 2) + (n << 4) + lq, kc)];
            #pragma unroll
            for (int m = 0; m < 4; ++m)
                #pragma unroll
                for (int n = 0; n < NF; ++n)
                    acc[m][n] = __builtin_amdgcn_mfma_f32_16x16x32_bf16(
                        af[m], bf[n], acc[m][n], 0, 0, 0);
        }
    }

    #pragma unroll
    for (int m = 0; m < 4; ++m)
        #pragma unroll
        for (int r = 0; r < 4; ++r) {
            const int row = rowBase + (wr << 6) + (m << 4) + (lg << 2) + r;
            #pragma unroll
            for (int n = 0; n < NF; ++n) {
                const int col = colBase + wc * (BN / 2) + (n << 4) + lq;
                float v = acc[m][n][r];
                if (BIAS) v += bias[col];
                if (OUT_BF16) ((u16*)Cout)[(size_t)row * N + col] = f2bf(v);
                else        ((float*)Cout)[(size_t)row * N + col] = v;
            }
        }
}

// ---------------------------------------------------------------------------
// V-part transpose: qkvb [token][2304] (cols h*192+128..191) -> vT[bh][d][token]
// Block = (bh, 64-token tile). LDS pad 66 -> column reads 2-way (free).
// ---------------------------------------------------------------------------
__global__ __launch_bounds__(256)
void vtrans_kernel(const u16* __restrict__ qkvb, u16* __restrict__ vT) {
    __shared__ u16 T[64][66];
    const int bh = blockIdx.y;
    const int tt = blockIdx.x;
    const int b = bh / NHEADS, h = bh % NHEADS;
    const int r  = threadIdx.x >> 2;
    const int dc = (threadIdx.x & 3) << 4;
    const u16* src = qkvb + (size_t)(b * SEQ + tt * 64 + r) * QKVD
                   + h * 192 + 128 + dc;
    *(s8v*)&T[r][dc]     = *(const s8v*)(src);
    *(s8v*)&T[r][dc + 8] = *(const s8v*)(src + 8);
    __syncthreads();
    const int d  = threadIdx.x >> 2;
    const int tc = (threadIdx.x & 3) << 4;
    s8v o0, o1;
    #pragma unroll
    for (int j = 0; j < 8; ++j) {
        o0[j] = (short)T[tc + j][d];
        o1[j] = (short)T[tc + 8 + j][d];
    }
    u16* dst = vT + ((size_t)bh * 64 + d) * SEQ + tt * 64 + tc;
    *(s8v*)dst = o0;
    *(s8v*)(dst + 8) = o1;
}

// ---------------------------------------------------------------------------
// MFMA flash attention. Block = (b,h, 64 q-rows), 4 waves x 16 q-rows.
// K and V^T staged via global_load_lds (pre-swizzled per-lane sources,
// linear LDS dest), double-buffered, ONE barrier per tile. Softmax
// denominator via in-register ones B-frag. Defer-max, cvt_pk P->bf16.
// LDS u16 map: K0@0 K1@4096 V0@8192 V1@12288 QP@16384  (40 KB total).
// ---------------------------------------------------------------------------
__global__ __launch_bounds__(256)
void attn_mfma(const u16* __restrict__ qkv, const u16* __restrict__ vT,
               u16* __restrict__ outb) {
    __shared__ u16 SL[20480];
    const int tid = threadIdx.x;
    const int l = tid & 63, w = tid >> 6;
    const int lq = l & 15, lg = l >> 4;
    const int q0 = blockIdx.x << 6;
    const int bh = blockIdx.y;
    const int b = bh / NHEADS, h = bh % NHEADS;
    const u16* base = qkv + (size_t)b * SEQ * QKVD + h * 192;
    const u16* vbh  = vT + (size_t)bh * 64 * SEQ;
    u16* QP = SL + 16384;

    // per-lane staging source offsets (elements) + wave-uniform LDS dests
    u32 koff[2], voff[2], dst2[2];
    {
        const int cs = l & 7;
        #pragma unroll
        for (int i = 0; i < 2; ++i) {
            const int row = (w << 4) + (i << 3) + (l >> 3);   // K key-row / V d-row
            koff[i] = (u32)(row * QKVD + 64 + ((cs ^ (row & 7)) << 3));
            voff[i] = (u32)(row * SEQ  +      ((cs ^ (row & 7)) << 3));
            dst2[i] = (u32)((w << 10) + (i << 9));
        }
    }

    {   // prologue: tile 0 -> buffer 0
        #pragma unroll
        for (int i = 0; i < 2; ++i) {
            GLOAD16(base + koff[i], &SL[dst2[i]]);
            GLOAD16(vbh  + voff[i], &SL[8192 + dst2[i]]);
        }
    }
    {   // stage Q
        const u16* qsrc = base + (size_t)(q0 + l) * QKVD;
        const s8v q1 = *(const s8v*)(qsrc + (w << 3));
        const s8v q2 = *(const s8v*)(qsrc + ((w + 4) << 3));
        *(s8v*)&QP[SW(l, (w << 3))] = q1;
        *(s8v*)&QP[SW(l, ((w + 4) << 3))] = q2;
    }
    __syncthreads();
    s8v qf[2];
    #pragma unroll
    for (int h2 = 0; h2 < 2; ++h2)
        qf[h2] = *(const s8v*)&QP[SW((w << 4) + lq, (h2 << 5) + (lg << 3))];

    s8v onesf;                       // denominator B-frag: col 64 <=> lq==0
    {
        const short o = (lq == 0) ? (short)0x3F80 : (short)0;
        #pragma unroll
        for (int e = 0; e < 8; ++e) onesf[e] = o;
    }

    f4v oacc[4], osum;
    #pragma unroll
    for (int db = 0; db < 4; ++db)
        #pragma unroll
        for (int r = 0; r < 4; ++r) oacc[db][r] = 0.f;
    #pragma unroll
    for (int r = 0; r < 4; ++r) osum[r] = 0.f;
    float mrun = -3.0e38f;

    for (int t = 0; t < 32; ++t) {
        const int par = t & 1;
        const u16* Kc = SL + (par << 12);
        const u16* Vc = SL + 8192 + (par << 12);

        // issue next tile's staging (completes at this iter's end barrier)
        if (t < 31) {
            const u16* sbK = base + (size_t)(t + 1) * (64 * QKVD);
            const u16* sbV = vbh + (t + 1) * 64;
            const u32 db_ = (u32)((par ^ 1) << 12);
            #pragma unroll
            for (int i = 0; i < 2; ++i) {
                GLOAD16(sbK + koff[i], &SL[db_ + dst2[i]]);
                GLOAD16(sbV + voff[i], &SL[8192 + db_ + dst2[i]]);
            }
        }

        // S^T = K Q^T : lane owns q=lq, keys kb*16+lg*4+r (raw scores)
        float p[16];
        __builtin_amdgcn_s_setprio(1);
        #pragma unroll
        for (int kb = 0; kb < 4; ++kb) {
            const s8v k0 = *(const s8v*)&Kc[SW((kb << 4) + lq, (lg << 3))];
            const s8v k1 = *(const s8v*)&Kc[SW((kb << 4) + lq, 32 + (lg << 3))];
            f4v z;
            #pragma unroll
            for (int r = 0; r < 4; ++r) z[r] = 0.f;
            z = __builtin_amdgcn_mfma_f32_16x16x32_bf16(k0, qf[0], z, 0, 0, 0);
            z = __builtin_amdgcn_mfma_f32_16x16x32_bf16(k1, qf[1], z, 0, 0, 0);
            #pragma unroll
            for (int r = 0; r < 4; ++r) p[(kb << 2) + r] = z[r];
        }
        __builtin_amdgcn_s_setprio(0);

        // defer-max softmax (local check only; cross-lane via ballot)
        float mx = p[0];
        #pragma unroll
        for (int i = 1; i < 16; ++i) mx = fmaxf(mx, p[i]);
        if (!__all(mx <= mrun + DEFER_THR)) {
            mx = fmaxf(mx, __shfl_xor(mx, 16));
            mx = fmaxf(mx, __shfl_xor(mx, 32));
            const float mn = fmaxf(mrun, mx);
            const float al = exp2f((mrun - mn) * CEXP);
            mrun = mn;
            float ar[4];
            #pragma unroll
            for (int r = 0; r < 4; ++r) ar[r] = __shfl(al, (lg << 2) + r);
            #pragma unroll
            for (int db = 0; db < 4; ++db)
                #pragma unroll
                for (int r = 0; r < 4; ++r) oacc[db][r] *= ar[r];
            #pragma unroll
            for (int r = 0; r < 4; ++r) osum[r] *= ar[r];
        }
        const float mC = -mrun * CEXP;
        #pragma unroll
        for (int i = 0; i < 16; ++i) p[i] = exp2f(fmaf(p[i], CEXP, mC));

        // P -> bf16 -> wave-private QP rows (b64 writes)
        #pragma unroll
        for (int kb = 0; kb < 4; ++kb) {
            u32x2 pw;
            pw[0] = cvtpk_bf16(p[(kb << 2) + 0], p[(kb << 2) + 1]);
            pw[1] = cvtpk_bf16(p[(kb << 2) + 2], p[(kb << 2) + 3]);
            *(u32x2*)&QP[SW((w << 4) + lq, (kb << 4) + (lg << 2))] = pw;
        }
        const s8v pf0 = *(const s8v*)&QP[SW((w << 4) + lq, (lg << 3))];
        const s8v pf1 = *(const s8v*)&QP[SW((w << 4) + lq, 32 + (lg << 3))];

        // PV (+ denominator via in-register ones-frag)
        __builtin_amdgcn_s_setprio(1);
        #pragma unroll
        for (int db = 0; db < 4; ++db) {
            const s8v v0 = *(const s8v*)&Vc[SW((db << 4) + lq, (lg << 3))];
            const s8v v1 = *(const s8v*)&Vc[SW((db << 4) + lq, 32 + (lg << 3))];
            oacc[db] = __builtin_amdgcn_mfma_f32_16x16x32_bf16(pf0, v0, oacc[db], 0, 0, 0);
            oacc[db] = __builtin_amdgcn_mfma_f32_16x16x32_bf16(pf1, v1, oacc[db], 0, 0, 0);
        }
        osum = __builtin_amdgcn_mfma_f32_16x16x32_bf16(pf0, onesf, osum, 0, 0, 0);
        osum = __builtin_amdgcn_mfma_f32_16x16x32_bf16(pf1, onesf, osum, 0, 0, 0);
        __builtin_amdgcn_s_setprio(0);

        __syncthreads();   // drains vmcnt (next tile staged) + all LDS reads
    }

    // epilogue: O[q'][d], q' = lg*4+r, d = db*16+lq; denom in lanes lq==0
    #pragma unroll
    for (int r = 0; r < 4; ++r) {
        const float li = __shfl(osum[r], l & 48);
        const float inv = 1.f / li;
        const size_t row = (size_t)b * SEQ + q0 + (w << 4) + (lg << 2) + r;
        #pragma unroll
        for (int db = 0; db < 4; ++db)
            outb[row * CD + h * 64 + (db << 4) + lq] = f2bf(oacc[db][r] * inv);
    }
}

// ---------------------------------------------------------------------------
extern "C" void kernel_launch(void* const* d_in, const int* in_sizes, int n_in,
                              void* d_out, int out_size, void* d_ws, size_t ws_size,
                              hipStream_t stream) {
    const float* x     = (const float*)d_in[0];
    const float* w_qkv = (const float*)d_in[1];
    const float* w_mlp = (const float*)d_in[2];
    const float* b_mlp = (const float*)d_in[3];
    float* out = (float*)d_out;

    const int NX  = BB * SEQ * CD;        // 3,145,728
    const int NWQ = QKVD * CD;            // 1,769,472
    const int NWM = CD * CD;              //   589,824
    const int NQK = BB * SEQ * QKVD;      // 9,437,184
    const int NAT = BB * SEQ * CD;        // attn out
    u16* xb    = (u16*)d_ws;
    u16* wqkvb = xb + NX;
    u16* wmlpb = wqkvb + NWQ;
    u16* qkvb  = wmlpb + NWM;
    u16* attnb = qkvb + NQK;
    u16* vTb   = attnb + NAT;             // [24][64][2048]

    cvt3_kernel<<<(NX + NWQ + NWM) / 2048, 256, 0, stream>>>(
        x, xb, NX, w_qkv, wqkvb, NWQ, w_mlp, wmlpb);

    const int M = BB * SEQ;   // 4096
    {   // qkv = x @ w_qkv^T  -> bf16
        dim3 grid(QKVD / 128, M / 128);
        gemm_bf16<128, true, false><<<grid, 256, 0, stream>>>(xb, wqkvb, nullptr,
                                                              qkvb, M, QKVD, CD);
    }
    {   // V-part transpose
        dim3 grid(SEQ / 64, BB * NHEADS);
        vtrans_kernel<<<grid, 256, 0, stream>>>(qkvb, vTb);
    }
    {   // attention
        dim3 grid(SEQ / 64, BB * NHEADS);
        attn_mfma<<<grid, 256, 0, stream>>>(qkvb, vTb, attnb);
    }
    {   // out = attn @ w_mlp^T + b  -> fp32
        dim3 grid(CD / 64, M / 128);
        gemm_bf16<64, false, true><<<grid, 256, 0, stream>>>(attnb, wmlpb, b_mlp,
                                                             out, M, CD, CD);
    }
}

// Round 7
// 93.109 us; speedup vs baseline: 1.4337x; 1.1617x over previous
//
#include <hip/hip_runtime.h>
#include <math.h>

typedef unsigned short u16;
typedef unsigned int   u32;
typedef __attribute__((ext_vector_type(8))) short s8v;   // 8 bf16 (4 VGPRs)
typedef __attribute__((ext_vector_type(2))) unsigned int u32x2;
typedef __attribute__((ext_vector_type(4))) float f4v;   // MFMA C/D

#define NHEADS 12
#define SEQ 2048
#define CD 768
#define BB 2
#define QKVD 2304
#define CEXP 0.18033688f      // 0.125 * log2(e)
#define DEFER_THR 44.0f       // exp2(44*CEXP) ~ 245, bf16-safe

__device__ inline u16 f2bf(float f) {            // RNE fp32->bf16
    union { float f; unsigned u; } v; v.f = f;
    unsigned r = v.u + 0x7FFFu + ((v.u >> 16) & 1u);
    return (u16)(r >> 16);
}
__device__ inline u32 cvtpk_bf16(float lo, float hi) {
    u32 r;
    asm("v_cvt_pk_bf16_f32 %0, %1, %2" : "=v"(r) : "v"(lo), "v"(hi));
    return r;
}
__device__ inline float exp2_fast(float x) {     // native v_exp_f32: D = 2^S0
    float r;
    asm("v_exp_f32 %0, %1" : "=v"(r) : "v"(x));
    return r;
}
__device__ inline float max3f(float a, float b, float c) {
    float r;
    asm("v_max3_f32 %0, %1, %2, %3" : "=v"(r) : "v"(a), "v"(b), "v"(c));
    return r;
}

#define GLOAD16(SRC, DST) __builtin_amdgcn_global_load_lds(                 \
    (const __attribute__((address_space(1))) void*)(SRC),                   \
    (__attribute__((address_space(3))) void*)(DST), 16, 0, 0)

// XOR swizzle for row-major [R][64] bf16 tiles (128B rows): u16 index
#define SW(r, c) ((((r) << 6) + (c)) ^ (((r) & 7) << 3))

// ---------------------------------------------------------------------------
__global__ __launch_bounds__(256)
void cvt3_kernel(const float* __restrict__ a, u16* __restrict__ oa, int na,
                 const float* __restrict__ b, u16* __restrict__ ob, int nb,
                 const float* __restrict__ c, u16* __restrict__ oc) {
    const int i = (blockIdx.x * 256 + threadIdx.x) * 8;
    const float* src; u16* dst;
    if (i < na)           { src = a + i;            dst = oa + i; }
    else if (i < na + nb) { src = b + (i - na);     dst = ob + (i - na); }
    else                  { src = c + (i - na - nb); dst = oc + (i - na - nb); }
    const float4 x = *(const float4*)src;
    const float4 y = *(const float4*)(src + 4);
    s8v o;
    o[0] = (short)f2bf(x.x); o[1] = (short)f2bf(x.y);
    o[2] = (short)f2bf(x.z); o[3] = (short)f2bf(x.w);
    o[4] = (short)f2bf(y.x); o[5] = (short)f2bf(y.y);
    o[6] = (short)f2bf(y.z); o[7] = (short)f2bf(y.w);
    *(s8v*)dst = o;
}

// ---------------------------------------------------------------------------
// C = A @ W^T (+bias). 128xBN tile, BK=64, 4 waves (unchanged).
// ---------------------------------------------------------------------------
template<int BN, bool OUT_BF16, bool BIAS>
__global__ __launch_bounds__(256)
void gemm_bf16(const u16* __restrict__ A, const u16* __restrict__ W,
               const float* __restrict__ bias, void* __restrict__ Cout,
               int M, int N, int K) {
    constexpr int NF = BN / 32;
    __shared__ u16 As[8192];
    __shared__ u16 Bs[BN * 64];
    const int tid = threadIdx.x;
    const int l  = tid & 63, w = tid >> 6;
    const int wr = w >> 1, wc = w & 1;
    const int lq = l & 15, lg = l >> 4;
    const int rowBase = blockIdx.y << 7, colBase = blockIdx.x * BN;

    f4v acc[4][NF];
    #pragma unroll
    for (int m = 0; m < 4; ++m)
        #pragma unroll
        for (int n = 0; n < NF; ++n)
            #pragma unroll
            for (int r = 0; r < 4; ++r) acc[m][n][r] = 0.f;

    const int chunk = l & 7;
    const int r8    = l >> 3;

    for (int kb = 0; kb < K; kb += 64) {
        __syncthreads();
        #pragma unroll
        for (int j = 0; j < 4; ++j) {
            const int rowA = (w << 5) + (j << 3) + r8;
            const int sc   = (chunk ^ (rowA & 7)) << 3;
            GLOAD16(A + (size_t)(rowBase + rowA) * K + kb + sc,
                    &As[(w << 11) + (j << 9)]);
        }
        #pragma unroll
        for (int j = 0; j < NF; ++j) {
            const int rowB = w * (BN / 4) + (j << 3) + r8;
            const int sc   = (chunk ^ (rowB & 7)) << 3;
            GLOAD16(W + (size_t)(colBase + rowB) * K + kb + sc,
                    &Bs[w * (BN * 16) + (j << 9)]);
        }
        __syncthreads();
        #pragma unroll
        for (int h = 0; h < 2; ++h) {
            const int kc = (h << 5) + (lg << 3);
            s8v af[4], bf[NF];
            #pragma unroll
            for (int m = 0; m < 4; ++m)
                af[m] = *(const s8v*)&As[SW((wr << 6) + (m << 4) + lq, kc)];
            #pragma unroll
            for (int n = 0; n < NF; ++n)
                bf[n] = *(const s8v*)&Bs[SW(wc * (BN / 2) + (n << 4) + lq, kc)];
            #pragma unroll
            for (int m = 0; m < 4; ++m)
                #pragma unroll
                for (int n = 0; n < NF; ++n)
                    acc[m][n] = __builtin_amdgcn_mfma_f32_16x16x32_bf16(
                        af[m], bf[n], acc[m][n], 0, 0, 0);
        }
    }

    #pragma unroll
    for (int m = 0; m < 4; ++m)
        #pragma unroll
        for (int r = 0; r < 4; ++r) {
            const int row = rowBase + (wr << 6) + (m << 4) + (lg << 2) + r;
            #pragma unroll
            for (int n = 0; n < NF; ++n) {
                const int col = colBase + wc * (BN / 2) + (n << 4) + lq;
                float v = acc[m][n][r];
                if (BIAS) v += bias[col];
                if (OUT_BF16) ((u16*)Cout)[(size_t)row * N + col] = f2bf(v);
                else        ((float*)Cout)[(size_t)row * N + col] = v;
            }
        }
}

// ---------------------------------------------------------------------------
// V-part transpose: qkvb [token][2304] (cols h*192+128..191) -> vT[bh][d][token]
// ---------------------------------------------------------------------------
__global__ __launch_bounds__(256)
void vtrans_kernel(const u16* __restrict__ qkvb, u16* __restrict__ vT) {
    __shared__ u16 T[64][66];
    const int bh = blockIdx.y;
    const int tt = blockIdx.x;
    const int b = bh / NHEADS, h = bh % NHEADS;
    const int r  = threadIdx.x >> 2;
    const int dc = (threadIdx.x & 3) << 4;
    const u16* src = qkvb + (size_t)(b * SEQ + tt * 64 + r) * QKVD
                   + h * 192 + 128 + dc;
    *(s8v*)&T[r][dc]     = *(const s8v*)(src);
    *(s8v*)&T[r][dc + 8] = *(const s8v*)(src + 8);
    __syncthreads();
    const int d  = threadIdx.x >> 2;
    const int tc = (threadIdx.x & 3) << 4;
    s8v o0, o1;
    #pragma unroll
    for (int j = 0; j < 8; ++j) {
        o0[j] = (short)T[tc + j][d];
        o1[j] = (short)T[tc + 8 + j][d];
    }
    u16* dst = vT + ((size_t)bh * 64 + d) * SEQ + tt * 64 + tc;
    *(s8v*)dst = o0;
    *(s8v*)(dst + 8) = o1;
}

// ---------------------------------------------------------------------------
// MFMA flash attention, 8 waves, in-block KV-split.
// Block = (b,h, 64 q-rows). Group g = w>>2 handles keys [g*1024, g*1024+1024),
// 16 tiles of 64. K and V^T staged via global_load_lds (pre-swizzled src),
// double-buffered, ONE barrier per tile. Denominator via ones-MFMA. Native
// v_exp_f32 / v_max3_f32. Partials merged through LDS at the end.
// LDS u16 map (81.5KB): Kg0@0/4096 Vg0@8192/12288 Kg1@16384/20480
// Vg1@24576/28672 QP@32768 (128rowsx64). Of32 spill aliases g1 K/V;
// Msh/Lsh alias QP.
// ---------------------------------------------------------------------------
__global__ __launch_bounds__(512)
void attn_mfma(const u16* __restrict__ qkv, const u16* __restrict__ vT,
               u16* __restrict__ outb) {
    __shared__ u16 SL[40960];
    const int tid = threadIdx.x;
    const int l = tid & 63, w = tid >> 6;     // w 0..7
    const int g = w >> 2, wl = w & 3;
    const int lq = l & 15, lg = l >> 4;
    const int q0 = blockIdx.x << 6;
    const int bh = blockIdx.y;
    const int b = bh / NHEADS, h = bh % NHEADS;
    const u16* base = qkv + (size_t)b * SEQ * QKVD + h * 192;
    const u16* vbh  = vT + (size_t)bh * 64 * SEQ;
    u16* QP = SL + 32768;
    float* Of32 = (float*)(SL + 16384);       // [64][64] f32, aliases g1 K/V
    float* Msh  = (float*)(SL + 32768);       // [64], aliases QP (post-loop)
    float* Lsh  = Msh + 64;

    const int kv0 = g << 10;                  // group key base

    // per-lane staging source offsets + wave-uniform LDS dest offsets
    u32 koff[2], voff[2], kdst[2], vdst[2];
    {
        const int cs = l & 7;
        #pragma unroll
        for (int i = 0; i < 2; ++i) {
            const int row = (wl << 4) + (i << 3) + (l >> 3);
            koff[i] = (u32)(row * QKVD + 64 + ((cs ^ (row & 7)) << 3));
            voff[i] = (u32)(row * SEQ  +      ((cs ^ (row & 7)) << 3));
            kdst[i] = (u32)((g << 14) + (wl << 10) + (i << 9));
            vdst[i] = (u32)((g << 14) + 8192 + (wl << 10) + (i << 9));
        }
    }

    {   // prologue: tile 0 of this group -> buffer 0
        const u16* sbK = base + (size_t)kv0 * QKVD;
        const u16* sbV = vbh + kv0;
        #pragma unroll
        for (int i = 0; i < 2; ++i) {
            GLOAD16(sbK + koff[i], &SL[kdst[i]]);
            GLOAD16(sbV + voff[i], &SL[vdst[i]]);
        }
    }
    {   // stage Q: 512 threads x 8 u16 covers [64][64]
        const s8v q1 = *(const s8v*)(base + (size_t)(q0 + l) * QKVD + (w << 3));
        *(s8v*)&QP[SW(l, w << 3)] = q1;
    }
    __syncthreads();
    s8v qf[2];
    #pragma unroll
    for (int h2 = 0; h2 < 2; ++h2)
        qf[h2] = *(const s8v*)&QP[SW((wl << 4) + lq, (h2 << 5) + (lg << 3))];

    s8v onesf;                       // denominator B-frag: col 0 <=> lq==0
    {
        const short o = (lq == 0) ? (short)0x3F80 : (short)0;
        #pragma unroll
        for (int e = 0; e < 8; ++e) onesf[e] = o;
    }
    f4v fz;                          // persistent zero C-operand
    #pragma unroll
    for (int r = 0; r < 4; ++r) fz[r] = 0.f;

    f4v oacc[4], osum;
    #pragma unroll
    for (int db = 0; db < 4; ++db)
        #pragma unroll
        for (int r = 0; r < 4; ++r) oacc[db][r] = 0.f;
    #pragma unroll
    for (int r = 0; r < 4; ++r) osum[r] = 0.f;
    float mrun = -3.0e38f;

    for (int t = 0; t < 16; ++t) {
        const int par = t & 1;
        const u16* Kc = SL + (g << 14) + (par << 12);
        const u16* Vc = SL + (g << 14) + 8192 + (par << 12);

        // issue next tile's staging into the other buffer
        if (t < 15) {
            const u16* sbK = base + (size_t)(kv0 + (t + 1) * 64) * QKVD;
            const u16* sbV = vbh + kv0 + (t + 1) * 64;
            const u32 pb = (u32)((par ^ 1) << 12);
            #pragma unroll
            for (int i = 0; i < 2; ++i) {
                GLOAD16(sbK + koff[i], &SL[kdst[i] + pb]);
                GLOAD16(sbV + voff[i], &SL[vdst[i] + pb]);
            }
        }

        // S^T = K Q^T : lane owns q=lq, keys kb*16+lg*4+r (raw scores)
        float p[16];
        __builtin_amdgcn_s_setprio(1);
        #pragma unroll
        for (int kb = 0; kb < 4; ++kb) {
            const s8v k0 = *(const s8v*)&Kc[SW((kb << 4) + lq, (lg << 3))];
            const s8v k1 = *(const s8v*)&Kc[SW((kb << 4) + lq, 32 + (lg << 3))];
            f4v z;
            z = __builtin_amdgcn_mfma_f32_16x16x32_bf16(k0, qf[0], fz, 0, 0, 0);
            z = __builtin_amdgcn_mfma_f32_16x16x32_bf16(k1, qf[1], z, 0, 0, 0);
            #pragma unroll
            for (int r = 0; r < 4; ++r) p[(kb << 2) + r] = z[r];
        }
        __builtin_amdgcn_s_setprio(0);

        // defer-max softmax (local check only; cross-lane via ballot)
        float m1_ = max3f(p[0], p[1], p[2]);
        float m2_ = max3f(p[3], p[4], p[5]);
        float m3_ = max3f(p[6], p[7], p[8]);
        float m4_ = max3f(p[9], p[10], p[11]);
        float m5_ = max3f(p[12], p[13], p[14]);
        float mx  = fmaxf(max3f(m1_, m2_, p[15]), max3f(m3_, m4_, m5_));
        if (!__all(mx <= mrun + DEFER_THR)) {
            mx = fmaxf(mx, __shfl_xor(mx, 16));
            mx = fmaxf(mx, __shfl_xor(mx, 32));
            const float mn = fmaxf(mrun, mx);
            const float al = exp2_fast((mrun - mn) * CEXP);
            mrun = mn;
            float ar[4];
            #pragma unroll
            for (int r = 0; r < 4; ++r) ar[r] = __shfl(al, (lg << 2) + r);
            #pragma unroll
            for (int db = 0; db < 4; ++db)
                #pragma unroll
                for (int r = 0; r < 4; ++r) oacc[db][r] *= ar[r];
            #pragma unroll
            for (int r = 0; r < 4; ++r) osum[r] *= ar[r];
        }
        const float mC = -mrun * CEXP;
        #pragma unroll
        for (int i = 0; i < 16; ++i) p[i] = exp2_fast(fmaf(p[i], CEXP, mC));

        // P -> bf16 -> wave-private QP rows [w*16, w*16+16)
        #pragma unroll
        for (int kb = 0; kb < 4; ++kb) {
            u32x2 pw;
            pw[0] = cvtpk_bf16(p[(kb << 2) + 0], p[(kb << 2) + 1]);
            pw[1] = cvtpk_bf16(p[(kb << 2) + 2], p[(kb << 2) + 3]);
            *(u32x2*)&QP[SW((w << 4) + lq, (kb << 4) + (lg << 2))] = pw;
        }
        const s8v pf0 = *(const s8v*)&QP[SW((w << 4) + lq, (lg << 3))];
        const s8v pf1 = *(const s8v*)&QP[SW((w << 4) + lq, 32 + (lg << 3))];

        // PV (+ denominator via in-register ones-frag)
        __builtin_amdgcn_s_setprio(1);
        #pragma unroll
        for (int db = 0; db < 4; ++db) {
            const s8v v0 = *(const s8v*)&Vc[SW((db << 4) + lq, (lg << 3))];
            const s8v v1 = *(const s8v*)&Vc[SW((db << 4) + lq, 32 + (lg << 3))];
            oacc[db] = __builtin_amdgcn_mfma_f32_16x16x32_bf16(pf0, v0, oacc[db], 0, 0, 0);
            oacc[db] = __builtin_amdgcn_mfma_f32_16x16x32_bf16(pf1, v1, oacc[db], 0, 0, 0);
        }
        osum = __builtin_amdgcn_mfma_f32_16x16x32_bf16(pf0, onesf, osum, 0, 0, 0);
        osum = __builtin_amdgcn_mfma_f32_16x16x32_bf16(pf1, onesf, osum, 0, 0, 0);
        __builtin_amdgcn_s_setprio(0);

        __syncthreads();   // drains own vmcnt (next tile staged) + LDS reads
    }

    // ---- merge group 1 -> group 0 through LDS ----
    if (g == 1) {
        if (lg == 0) Msh[(wl << 4) + lq] = mrun;
        if (lq == 0) {
            #pragma unroll
            for (int r = 0; r < 4; ++r)
                Lsh[(wl << 4) + (lg << 2) + r] = osum[r];
        }
        #pragma unroll
        for (int db = 0; db < 4; ++db)
            #pragma unroll
            for (int r = 0; r < 4; ++r)
                Of32[(((wl << 4) + (lg << 2) + r) << 6) + (db << 4) + lq] =
                    oacc[db][r];
    }
    __syncthreads();
    if (g == 0) {
        #pragma unroll
        for (int r = 0; r < 4; ++r) {
            const int rowq = (wl << 4) + (lg << 2) + r;
            const float m0r = __shfl(mrun, (lg << 2) + r);
            const float l0r = __shfl(osum[r], l & 48);
            const float m1r = Msh[rowq];
            const float l1r = Lsh[rowq];
            const float M   = fmaxf(m0r, m1r);
            const float w0  = exp2_fast((m0r - M) * CEXP);
            const float w1  = exp2_fast((m1r - M) * CEXP);
            const float inv = 1.f / (l0r * w0 + l1r * w1);
            const float a0 = w0 * inv, a1 = w1 * inv;
            const size_t row = (size_t)b * SEQ + q0 + rowq;
            #pragma unroll
            for (int db = 0; db < 4; ++db) {
                const float o1 = Of32[(rowq << 6) + (db << 4) + lq];
                outb[row * CD + h * 64 + (db << 4) + lq] =
                    f2bf(oacc[db][r] * a0 + o1 * a1);
            }
        }
    }
}

// ---------------------------------------------------------------------------
extern "C" void kernel_launch(void* const* d_in, const int* in_sizes, int n_in,
                              void* d_out, int out_size, void* d_ws, size_t ws_size,
                              hipStream_t stream) {
    const float* x     = (const float*)d_in[0];
    const float* w_qkv = (const float*)d_in[1];
    const float* w_mlp = (const float*)d_in[2];
    const float* b_mlp = (const float*)d_in[3];
    float* out = (float*)d_out;

    const int NX  = BB * SEQ * CD;        // 3,145,728
    const int NWQ = QKVD * CD;            // 1,769,472
    const int NWM = CD * CD;              //   589,824
    const int NQK = BB * SEQ * QKVD;      // 9,437,184
    const int NAT = BB * SEQ * CD;        // attn out
    u16* xb    = (u16*)d_ws;
    u16* wqkvb = xb + NX;
    u16* wmlpb = wqkvb + NWQ;
    u16* qkvb  = wmlpb + NWM;
    u16* attnb = qkvb + NQK;
    u16* vTb   = attnb + NAT;             // [24][64][2048]

    cvt3_kernel<<<(NX + NWQ + NWM) / 2048, 256, 0, stream>>>(
        x, xb, NX, w_qkv, wqkvb, NWQ, w_mlp, wmlpb);

    const int M = BB * SEQ;   // 4096
    {   // qkv = x @ w_qkv^T  -> bf16
        dim3 grid(QKVD / 128, M / 128);
        gemm_bf16<128, true, false><<<grid, 256, 0, stream>>>(xb, wqkvb, nullptr,
                                                              qkvb, M, QKVD, CD);
    }
    {   // V-part transpose
        dim3 grid(SEQ / 64, BB * NHEADS);
        vtrans_kernel<<<grid, 256, 0, stream>>>(qkvb, vTb);
    }
    {   // attention (8 waves, in-block KV-split)
        dim3 grid(SEQ / 64, BB * NHEADS);
        attn_mfma<<<grid, 512, 0, stream>>>(qkvb, vTb, attnb);
    }
    {   // out = attn @ w_mlp^T + b  -> fp32
        dim3 grid(CD / 64, M / 128);
        gemm_bf16<64, false, true><<<grid, 256, 0, stream>>>(attnb, wmlpb, b_mlp,
                                                             out, M, CD, CD);
    }
}

// Round 8
// 91.006 us; speedup vs baseline: 1.4668x; 1.0231x over previous
//
#include <hip/hip_runtime.h>
#include <math.h>

typedef unsigned short u16;
typedef unsigned int   u32;
typedef __attribute__((ext_vector_type(8))) short s8v;   // 8 bf16 (4 VGPRs)
typedef __attribute__((ext_vector_type(2))) unsigned int u32x2;
typedef __attribute__((ext_vector_type(4))) float f4v;   // MFMA C/D

#define NHEADS 12
#define SEQ 2048
#define CD 768
#define BB 2
#define QKVD 2304
#define CEXP 0.18033688f      // 0.125 * log2(e)
#define DEFER_THR 44.0f       // exp2(44*CEXP) ~ 245, bf16-safe

__device__ inline u16 f2bf(float f) {            // RNE fp32->bf16
    union { float f; unsigned u; } v; v.f = f;
    unsigned r = v.u + 0x7FFFu + ((v.u >> 16) & 1u);
    return (u16)(r >> 16);
}
__device__ inline u32 cvtpk_bf16(float lo, float hi) {
    u32 r;
    asm("v_cvt_pk_bf16_f32 %0, %1, %2" : "=v"(r) : "v"(lo), "v"(hi));
    return r;
}
__device__ inline float exp2_fast(float x) {     // native v_exp_f32: D = 2^S0
    float r;
    asm("v_exp_f32 %0, %1" : "=v"(r) : "v"(x));
    return r;
}
__device__ inline float max3f(float a, float b, float c) {
    float r;
    asm("v_max3_f32 %0, %1, %2, %3" : "=v"(r) : "v"(a), "v"(b), "v"(c));
    return r;
}

#define GLOAD16(SRC, DST) __builtin_amdgcn_global_load_lds(                 \
    (const __attribute__((address_space(1))) void*)(SRC),                   \
    (__attribute__((address_space(3))) void*)(DST), 16, 0, 0)

// XOR swizzle for row-major [R][64] bf16 tiles (128B rows): u16 index
#define SW(r, c) ((((r) << 6) + (c)) ^ (((r) & 7) << 3))

// ---------------------------------------------------------------------------
__global__ __launch_bounds__(256)
void cvt3_kernel(const float* __restrict__ a, u16* __restrict__ oa, int na,
                 const float* __restrict__ b, u16* __restrict__ ob, int nb,
                 const float* __restrict__ c, u16* __restrict__ oc) {
    const int i = (blockIdx.x * 256 + threadIdx.x) * 8;
    const float* src; u16* dst;
    if (i < na)           { src = a + i;            dst = oa + i; }
    else if (i < na + nb) { src = b + (i - na);     dst = ob + (i - na); }
    else                  { src = c + (i - na - nb); dst = oc + (i - na - nb); }
    const float4 x = *(const float4*)src;
    const float4 y = *(const float4*)(src + 4);
    s8v o;
    o[0] = (short)f2bf(x.x); o[1] = (short)f2bf(x.y);
    o[2] = (short)f2bf(x.z); o[3] = (short)f2bf(x.w);
    o[4] = (short)f2bf(y.x); o[5] = (short)f2bf(y.y);
    o[6] = (short)f2bf(y.z); o[7] = (short)f2bf(y.w);
    *(s8v*)dst = o;
}

// ---------------------------------------------------------------------------
// C = A @ W^T (+bias). 128xBN tile, BK=64, 4 waves. 1-D grid, XCD-swizzled.
// NBX = number of column tiles (grid.x = NBX * M/128, must be %8==0).
// ---------------------------------------------------------------------------
template<int BN, int NBX, bool OUT_BF16, bool BIAS>
__global__ __launch_bounds__(256)
void gemm_bf16(const u16* __restrict__ A, const u16* __restrict__ W,
               const float* __restrict__ bias, void* __restrict__ Cout,
               int M, int N, int K) {
    constexpr int NF = BN / 32;
    __shared__ u16 As[8192];
    __shared__ u16 Bs[BN * 64];
    const int tid = threadIdx.x;
    const int l  = tid & 63, w = tid >> 6;
    const int wr = w >> 1, wc = w & 1;
    const int lq = l & 15, lg = l >> 4;

    // XCD-chunked swizzle (bijective since gridDim.x % 8 == 0)
    const int fid = blockIdx.x;
    const int cpx = gridDim.x >> 3;
    const int swz = (fid & 7) * cpx + (fid >> 3);
    const int rowBase = (swz / NBX) << 7;
    const int colBase = (swz % NBX) * BN;

    f4v acc[4][NF];
    #pragma unroll
    for (int m = 0; m < 4; ++m)
        #pragma unroll
        for (int n = 0; n < NF; ++n)
            #pragma unroll
            for (int r = 0; r < 4; ++r) acc[m][n][r] = 0.f;

    const int chunk = l & 7;
    const int r8    = l >> 3;

    for (int kb = 0; kb < K; kb += 64) {
        __syncthreads();
        #pragma unroll
        for (int j = 0; j < 4; ++j) {
            const int rowA = (w << 5) + (j << 3) + r8;
            const int sc   = (chunk ^ (rowA & 7)) << 3;
            GLOAD16(A + (size_t)(rowBase + rowA) * K + kb + sc,
                    &As[(w << 11) + (j << 9)]);
        }
        #pragma unroll
        for (int j = 0; j < NF; ++j) {
            const int rowB = w * (BN / 4) + (j << 3) + r8;
            const int sc   = (chunk ^ (rowB & 7)) << 3;
            GLOAD16(W + (size_t)(colBase + rowB) * K + kb + sc,
                    &Bs[w * (BN * 16) + (j << 9)]);
        }
        __syncthreads();
        #pragma unroll
        for (int h = 0; h < 2; ++h) {
            const int kc = (h << 5) + (lg << 3);
            s8v af[4], bf[NF];
            #pragma unroll
            for (int m = 0; m < 4; ++m)
                af[m] = *(const s8v*)&As[SW((wr << 6) + (m << 4) + lq, kc)];
            #pragma unroll
            for (int n = 0; n < NF; ++n)
                bf[n] = *(const s8v*)&Bs[SW(wc * (BN / 2) + (n << 4) + lq, kc)];
            #pragma unroll
            for (int m = 0; m < 4; ++m)
                #pragma unroll
                for (int n = 0; n < NF; ++n)
                    acc[m][n] = __builtin_amdgcn_mfma_f32_16x16x32_bf16(
                        af[m], bf[n], acc[m][n], 0, 0, 0);
        }
    }

    #pragma unroll
    for (int m = 0; m < 4; ++m)
        #pragma unroll
        for (int r = 0; r < 4; ++r) {
            const int row = rowBase + (wr << 6) + (m << 4) + (lg << 2) + r;
            #pragma unroll
            for (int n = 0; n < NF; ++n) {
                const int col = colBase + wc * (BN / 2) + (n << 4) + lq;
                float v = acc[m][n][r];
                if (BIAS) v += bias[col];
                if (OUT_BF16) ((u16*)Cout)[(size_t)row * N + col] = f2bf(v);
                else        ((float*)Cout)[(size_t)row * N + col] = v;
            }
        }
}

// ---------------------------------------------------------------------------
// V-part transpose: qkvb [token][2304] (cols h*192+128..191) -> vT[bh][d][token]
// ---------------------------------------------------------------------------
__global__ __launch_bounds__(256)
void vtrans_kernel(const u16* __restrict__ qkvb, u16* __restrict__ vT) {
    __shared__ u16 T[64][66];
    const int bh = blockIdx.y;
    const int tt = blockIdx.x;
    const int b = bh / NHEADS, h = bh % NHEADS;
    const int r  = threadIdx.x >> 2;
    const int dc = (threadIdx.x & 3) << 4;
    const u16* src = qkvb + (size_t)(b * SEQ + tt * 64 + r) * QKVD
                   + h * 192 + 128 + dc;
    *(s8v*)&T[r][dc]     = *(const s8v*)(src);
    *(s8v*)&T[r][dc + 8] = *(const s8v*)(src + 8);
    __syncthreads();
    const int d  = threadIdx.x >> 2;
    const int tc = (threadIdx.x & 3) << 4;
    s8v o0, o1;
    #pragma unroll
    for (int j = 0; j < 8; ++j) {
        o0[j] = (short)T[tc + j][d];
        o1[j] = (short)T[tc + 8 + j][d];
    }
    u16* dst = vT + ((size_t)bh * 64 + d) * SEQ + tt * 64 + tc;
    *(s8v*)dst = o0;
    *(s8v*)(dst + 8) = o1;
}

// ---------------------------------------------------------------------------
// MFMA flash attention, 8 waves, in-block KV-split, SINGLE-buffered K/V.
// Grid: 768 1-D, XCD-chunked swizzle (each XCD serves 3 heads -> L2-resident
// K/V/vT). Group g = w>>2 handles keys [g*1024, +1024), 16 tiles of 64.
// Per tile: [top barrier: staged data visible] QK -> [barrier: K reads done]
// -> stage K(t+1) (latency hides under softmax+PV) -> softmax/P/PV ->
// [barrier: V reads done] -> stage V(t+1).
// LDS 48KB (3 blocks/CU, grid = 3/CU exactly, no tail):
//   Kg@g*8192, Vg@g*8192+4096 (u16 idx), QP@16384 (rows 0..127).
//   Of32 merge spill aliases g1 K/V; Msh/Lsh alias QP (post-loop).
// ---------------------------------------------------------------------------
__global__ __launch_bounds__(512)
void attn_mfma(const u16* __restrict__ qkv, const u16* __restrict__ vT,
               u16* __restrict__ outb) {
    __shared__ u16 SL[24576];
    const int tid = threadIdx.x;
    const int l = tid & 63, w = tid >> 6;     // w 0..7
    const int g = w >> 2, wl = w & 3;
    const int lq = l & 15, lg = l >> 4;

    // XCD-chunked swizzle over 768 blocks (768 % 8 == 0 -> bijective)
    const int fid = blockIdx.x;
    const int swz = (fid & 7) * 96 + (fid >> 3);
    const int q0 = (swz & 31) << 6;
    const int bh = swz >> 5;
    const int b = bh / NHEADS, h = bh % NHEADS;
    const u16* base = qkv + (size_t)b * SEQ * QKVD + h * 192;
    const u16* vbh  = vT + (size_t)bh * 64 * SEQ;
    u16* QP = SL + 16384;
    float* Of32 = (float*)(SL + 8192);        // [64][64] f32, aliases g1 K/V
    float* Msh  = (float*)(SL + 16384);       // [64], aliases QP (post-loop)
    float* Lsh  = Msh + 64;

    const int kv0 = g << 10;                  // group key base

    // per-lane staging source offsets + wave-uniform LDS dest offsets
    u32 koff[2], voff[2], kdst[2], vdst[2];
    {
        const int cs = l & 7;
        #pragma unroll
        for (int i = 0; i < 2; ++i) {
            const int row = (wl << 4) + (i << 3) + (l >> 3);
            koff[i] = (u32)(row * QKVD + 64 + ((cs ^ (row & 7)) << 3));
            voff[i] = (u32)(row * SEQ  +      ((cs ^ (row & 7)) << 3));
            kdst[i] = (u32)((g << 13) + (wl << 10) + (i << 9));
            vdst[i] = (u32)((g << 13) + 4096 + (wl << 10) + (i << 9));
        }
    }

    {   // prologue: stage tile 0 (K and V)
        const u16* sbK = base + (size_t)kv0 * QKVD;
        const u16* sbV = vbh + kv0;
        #pragma unroll
        for (int i = 0; i < 2; ++i) {
            GLOAD16(sbK + koff[i], &SL[kdst[i]]);
            GLOAD16(sbV + voff[i], &SL[vdst[i]]);
        }
    }
    {   // stage Q: 512 threads x 8 u16 covers [64][64]
        const s8v q1 = *(const s8v*)(base + (size_t)(q0 + l) * QKVD + (w << 3));
        *(s8v*)&QP[SW(l, w << 3)] = q1;
    }
    __syncthreads();               // Q visible; own tile-0 gloads drained
    s8v qf[2];
    #pragma unroll
    for (int h2 = 0; h2 < 2; ++h2)
        qf[h2] = *(const s8v*)&QP[SW((wl << 4) + lq, (h2 << 5) + (lg << 3))];

    s8v onesf;                       // denominator B-frag: col 0 <=> lq==0
    {
        const short o = (lq == 0) ? (short)0x3F80 : (short)0;
        #pragma unroll
        for (int e = 0; e < 8; ++e) onesf[e] = o;
    }
    f4v fz;                          // persistent zero C-operand
    #pragma unroll
    for (int r = 0; r < 4; ++r) fz[r] = 0.f;

    f4v oacc[4], osum;
    #pragma unroll
    for (int db = 0; db < 4; ++db)
        #pragma unroll
        for (int r = 0; r < 4; ++r) oacc[db][r] = 0.f;
    #pragma unroll
    for (int r = 0; r < 4; ++r) osum[r] = 0.f;
    float mrun = -3.0e38f;

    const u16* Kc = SL + (g << 13);
    const u16* Vc = Kc + 4096;

    for (int t = 0; t < 16; ++t) {
        // top barrier: all waves' qf reads done (tile 0) / staged K,V visible
        __syncthreads();

        // S^T = K Q^T : lane owns q=lq, keys kb*16+lg*4+r (raw scores)
        float p[16];
        __builtin_amdgcn_s_setprio(1);
        #pragma unroll
        for (int kb = 0; kb < 4; ++kb) {
            const s8v k0 = *(const s8v*)&Kc[SW((kb << 4) + lq, (lg << 3))];
            const s8v k1 = *(const s8v*)&Kc[SW((kb << 4) + lq, 32 + (lg << 3))];
            f4v z;
            z = __builtin_amdgcn_mfma_f32_16x16x32_bf16(k0, qf[0], fz, 0, 0, 0);
            z = __builtin_amdgcn_mfma_f32_16x16x32_bf16(k1, qf[1], z, 0, 0, 0);
            #pragma unroll
            for (int r = 0; r < 4; ++r) p[(kb << 2) + r] = z[r];
        }
        __builtin_amdgcn_s_setprio(0);

        __syncthreads();           // all waves done reading K(t)
        if (t < 15) {              // stage K(t+1); hides under softmax+PV
            const u16* sbK = base + (size_t)(kv0 + (t + 1) * 64) * QKVD;
            #pragma unroll
            for (int i = 0; i < 2; ++i)
                GLOAD16(sbK + koff[i], &SL[kdst[i]]);
        }

        // defer-max softmax (local check only; cross-lane via ballot)
        float m1_ = max3f(p[0], p[1], p[2]);
        float m2_ = max3f(p[3], p[4], p[5]);
        float m3_ = max3f(p[6], p[7], p[8]);
        float m4_ = max3f(p[9], p[10], p[11]);
        float m5_ = max3f(p[12], p[13], p[14]);
        float mx  = fmaxf(max3f(m1_, m2_, p[15]), max3f(m3_, m4_, m5_));
        if (!__all(mx <= mrun + DEFER_THR)) {
            mx = fmaxf(mx, __shfl_xor(mx, 16));
            mx = fmaxf(mx, __shfl_xor(mx, 32));
            const float mn = fmaxf(mrun, mx);
            const float al = exp2_fast((mrun - mn) * CEXP);
            mrun = mn;
            float ar[4];
            #pragma unroll
            for (int r = 0; r < 4; ++r) ar[r] = __shfl(al, (lg << 2) + r);
            #pragma unroll
            for (int db = 0; db < 4; ++db)
                #pragma unroll
                for (int r = 0; r < 4; ++r) oacc[db][r] *= ar[r];
            #pragma unroll
            for (int r = 0; r < 4; ++r) osum[r] *= ar[r];
        }
        const float mC = -mrun * CEXP;
        #pragma unroll
        for (int i = 0; i < 16; ++i) p[i] = exp2_fast(fmaf(p[i], CEXP, mC));

        // P -> bf16 -> wave-private QP rows [w*16, w*16+16)
        #pragma unroll
        for (int kb = 0; kb < 4; ++kb) {
            u32x2 pw;
            pw[0] = cvtpk_bf16(p[(kb << 2) + 0], p[(kb << 2) + 1]);
            pw[1] = cvtpk_bf16(p[(kb << 2) + 2], p[(kb << 2) + 3]);
            *(u32x2*)&QP[SW((w << 4) + lq, (kb << 4) + (lg << 2))] = pw;
        }
        const s8v pf0 = *(const s8v*)&QP[SW((w << 4) + lq, (lg << 3))];
        const s8v pf1 = *(const s8v*)&QP[SW((w << 4) + lq, 32 + (lg << 3))];

        // PV (+ denominator via in-register ones-frag)
        __builtin_amdgcn_s_setprio(1);
        #pragma unroll
        for (int db = 0; db < 4; ++db) {
            const s8v v0 = *(const s8v*)&Vc[SW((db << 4) + lq, (lg << 3))];
            const s8v v1 = *(const s8v*)&Vc[SW((db << 4) + lq, 32 + (lg << 3))];
            oacc[db] = __builtin_amdgcn_mfma_f32_16x16x32_bf16(pf0, v0, oacc[db], 0, 0, 0);
            oacc[db] = __builtin_amdgcn_mfma_f32_16x16x32_bf16(pf1, v1, oacc[db], 0, 0, 0);
        }
        osum = __builtin_amdgcn_mfma_f32_16x16x32_bf16(pf0, onesf, osum, 0, 0, 0);
        osum = __builtin_amdgcn_mfma_f32_16x16x32_bf16(pf1, onesf, osum, 0, 0, 0);
        __builtin_amdgcn_s_setprio(0);

        __syncthreads();           // all waves done reading V(t)
        if (t < 15) {              // stage V(t+1)
            const u16* sbV = vbh + kv0 + (t + 1) * 64;
            #pragma unroll
            for (int i = 0; i < 2; ++i)
                GLOAD16(sbV + voff[i], &SL[vdst[i]]);
        }
    }

    // ---- merge group 1 -> group 0 through LDS ----
    if (g == 1) {
        if (lg == 0) Msh[(wl << 4) + lq] = mrun;
        if (lq == 0) {
            #pragma unroll
            for (int r = 0; r < 4; ++r)
                Lsh[(wl << 4) + (lg << 2) + r] = osum[r];
        }
        #pragma unroll
        for (int db = 0; db < 4; ++db)
            #pragma unroll
            for (int r = 0; r < 4; ++r)
                Of32[(((wl << 4) + (lg << 2) + r) << 6) + (db << 4) + lq] =
                    oacc[db][r];
    }
    __syncthreads();
    if (g == 0) {
        #pragma unroll
        for (int r = 0; r < 4; ++r) {
            const int rowq = (wl << 4) + (lg << 2) + r;
            const float m0r = __shfl(mrun, (lg << 2) + r);
            const float l0r = __shfl(osum[r], l & 48);
            const float m1r = Msh[rowq];
            const float l1r = Lsh[rowq];
            const float M   = fmaxf(m0r, m1r);
            const float w0  = exp2_fast((m0r - M) * CEXP);
            const float w1  = exp2_fast((m1r - M) * CEXP);
            const float inv = 1.f / (l0r * w0 + l1r * w1);
            const float a0 = w0 * inv, a1 = w1 * inv;
            const size_t row = (size_t)b * SEQ + q0 + rowq;
            #pragma unroll
            for (int db = 0; db < 4; ++db) {
                const float o1 = Of32[(rowq << 6) + (db << 4) + lq];
                outb[row * CD + h * 64 + (db << 4) + lq] =
                    f2bf(oacc[db][r] * a0 + o1 * a1);
            }
        }
    }
}

// ---------------------------------------------------------------------------
extern "C" void kernel_launch(void* const* d_in, const int* in_sizes, int n_in,
                              void* d_out, int out_size, void* d_ws, size_t ws_size,
                              hipStream_t stream) {
    const float* x     = (const float*)d_in[0];
    const float* w_qkv = (const float*)d_in[1];
    const float* w_mlp = (const float*)d_in[2];
    const float* b_mlp = (const float*)d_in[3];
    float* out = (float*)d_out;

    const int NX  = BB * SEQ * CD;        // 3,145,728
    const int NWQ = QKVD * CD;            // 1,769,472
    const int NWM = CD * CD;              //   589,824
    const int NQK = BB * SEQ * QKVD;      // 9,437,184
    const int NAT = BB * SEQ * CD;        // attn out
    u16* xb    = (u16*)d_ws;
    u16* wqkvb = xb + NX;
    u16* wmlpb = wqkvb + NWQ;
    u16* qkvb  = wmlpb + NWM;
    u16* attnb = qkvb + NQK;
    u16* vTb   = attnb + NAT;             // [24][64][2048]

    cvt3_kernel<<<(NX + NWQ + NWM) / 2048, 256, 0, stream>>>(
        x, xb, NX, w_qkv, wqkvb, NWQ, w_mlp, wmlpb);

    const int M = BB * SEQ;   // 4096
    {   // qkv = x @ w_qkv^T  -> bf16   (grid 576 = 18 cols x 32 rows)
        gemm_bf16<128, 18, true, false><<<576, 256, 0, stream>>>(
            xb, wqkvb, nullptr, qkvb, M, QKVD, CD);
    }
    {   // V-part transpose
        dim3 grid(SEQ / 64, BB * NHEADS);
        vtrans_kernel<<<grid, 256, 0, stream>>>(qkvb, vTb);
    }
    {   // attention (8 waves, KV-split, 3 blocks/CU, XCD swizzle)
        attn_mfma<<<768, 512, 0, stream>>>(qkvb, vTb, attnb);
    }
    {   // out = attn @ w_mlp^T + b  -> fp32 (grid 384 = 12 cols x 32 rows)
        gemm_bf16<64, 12, false, true><<<384, 256, 0, stream>>>(
            attnb, wmlpb, b_mlp, out, M, CD, CD);
    }
}